// Round 8
// baseline (427.415 us; speedup 1.0000x reference)
//
#include <hip/hip_runtime.h>
#include <math.h>

#define D 66
#define YR 64                 // main row stride (floats): 256B rows, 64B-segment aligned
#define NEG_SLOPE 0.2f
#define CAP 6144

typedef short s8v __attribute__((ext_vector_type(8)));   // 8 bf16 bit-patterns = 4 VGPRs
typedef float f4v __attribute__((ext_vector_type(4)));

__device__ __forceinline__ float lrelu(float a){ return a > 0.f ? a : NEG_SLOPE * a; }
__device__ __forceinline__ void fma4(float4& a, float s, const float4& w){
  a.x = fmaf(s, w.x, a.x); a.y = fmaf(s, w.y, a.y);
  a.z = fmaf(s, w.z, a.z); a.w = fmaf(s, w.w, a.w);
}
__device__ __forceinline__ unsigned short bf16r(float f){   // RNE f32->bf16
  unsigned u = __float_as_uint(f);
  u += 0x7FFFu + ((u >> 16) & 1u);
  return (unsigned short)(u >> 16);
}
__device__ __forceinline__ float bf16f(unsigned short b){
  return __uint_as_float(((unsigned)b) << 16);
}
// 2-term RNE split: v = a0 + a1 + r, a0 = rne16(v), r1 = v - a0 (EXACT in fp32),
// a1 = rne16(r1). |r| <= 2^-18 |v|, unbiased. Same decomposition as the W pack.
__device__ __forceinline__ void split8d(const float* p, s8v& a0, s8v& a1){
  #pragma unroll
  for (int j = 0; j < 8; j++){
    float v = p[j];
    unsigned short h0 = bf16r(v);
    float r1 = v - bf16f(h0);
    a0[j] = (short)h0;
    a1[j] = (short)bf16r(r1);
  }
}
#define MM4(acc, a0, a1, b0v, b1v)                                         \
  acc = __builtin_amdgcn_mfma_f32_16x16x32_bf16(a0, b0v, acc, 0, 0, 0);    \
  acc = __builtin_amdgcn_mfma_f32_16x16x32_bf16(a1, b0v, acc, 0, 0, 0);    \
  acc = __builtin_amdgcn_mfma_f32_16x16x32_bf16(a0, b1v, acc, 0, 0, 0);    \
  acc = __builtin_amdgcn_mfma_f32_16x16x32_bf16(a1, b1v, acc, 0, 0, 0);

// ---------------- BN stats (deterministic per-block partials) + bucket hist ----------------
__global__ __launch_bounds__(256) void k_stats_hist(const float* __restrict__ h, const int* __restrict__ dst,
                                                    float* __restrict__ partials, int* __restrict__ bhist,
                                                    int n, int E){
  int t = threadIdx.x;
  if (blockIdx.x < 256){
    __shared__ float ls[3 * 2 * D];
    int rpb = (n + 255) / 256;
    int r0 = blockIdx.x * rpb;
    int r1 = min(n, r0 + rpb);
    if (t < 3 * D){
      int c = t % D, seg = t / D;
      float s1 = 0.f, s2 = 0.f;
      for (int r = r0 + seg; r < r1; r += 3){
        float v = h[(size_t)r * D + c];
        s1 += v; s2 += v * v;
      }
      ls[seg * 2 * D + c]     = s1;   // direct store, no atomic
      ls[seg * 2 * D + D + c] = s2;
    }
    __syncthreads();
    if (t < 2 * D){
      float p = ls[t] + ls[2 * D + t] + ls[4 * D + t];   // fixed combine order
      partials[(size_t)t * 256 + blockIdx.x] = p;
    }
  } else {
    __shared__ int hh[256];
    hh[t] = 0;
    __syncthreads();
    int stride = 256 * 256;
    for (int e = (blockIdx.x - 256) * 256 + t; e < E; e += stride)
      atomicAdd(&hh[dst[e] >> 8], 1);                    // integer: value-deterministic
    __syncthreads();
    if (hh[t]) atomicAdd(&bhist[t], hh[t]);
  }
}

// ---------------- merged prep: BN finalize (fixed-order reduce) + GAT pack + FC pack ----------------
struct PrepArgs {
  const float *part, *gamma, *beta;
  const float *We[3], *ae[3];
  const float *gw[3];
  const float *fw[5], *fb[5];
  float *misc; short *W0, *W1; short *F0, *F1; float *bpack;
  int n;
};

__global__ __launch_bounds__(256) void k_prep(PrepArgs pa){
  int t = threadIdx.x;
  if (blockIdx.x == 0){
    if (t < D){
      const float4* pm = (const float4*)(pa.part + (size_t)t * 256);
      const float4* pv = (const float4*)(pa.part + (size_t)(D + t) * 256);
      float4 am = make_float4(0.f,0.f,0.f,0.f), av = make_float4(0.f,0.f,0.f,0.f);
      #pragma unroll 8
      for (int b = 0; b < 64; b++){
        float4 m4 = pm[b], v4 = pv[b];
        am.x += m4.x; am.y += m4.y; am.z += m4.z; am.w += m4.w;
        av.x += v4.x; av.y += v4.y; av.z += v4.z; av.w += v4.w;
      }
      float s1 = (am.x + am.y) + (am.z + am.w);
      float s2 = (av.x + av.y) + (av.z + av.w);
      float mean = s1 / (float)pa.n;
      float var  = s2 / (float)pa.n - mean * mean;
      float inv  = rsqrtf(var + 1e-5f);
      float sc = pa.gamma[t] * inv;
      pa.misc[t] = sc;
      pa.misc[D + t] = pa.beta[t] - mean * sc;
    } else if (t >= D && t < D + 3){
      int l = t - D;
      float c = 0.f;
      for (int d = 0; d < D; d++) c += pa.We[l][d] * pa.ae[l][d];
      pa.misc[2 * D + l] = c;
    }
  } else if (blockIdx.x <= 12){
    int tid = (blockIdx.x - 1) * 256 + t;
    if (tid >= 3 * 960) return;
    int L = tid & 63;
    int ct = (tid >> 6) % 15;
    int lay = tid / 960;
    const float* w = pa.gw[lay];
    int c = ct / 5, tt = ct % 5;
    int nn = tt * 16 + (L & 15);
    int kb = c * 32 + (L >> 4) * 8;
    #pragma unroll
    for (int j = 0; j < 8; j++){
      int k = kb + j;
      float v = (k < D && nn < D) ? w[k * D + nn] : 0.f;
      unsigned short b0 = bf16r(v);
      float r1 = v - bf16f(b0);
      unsigned short b1 = bf16r(r1);
      pa.W0[tid * 8 + j] = (short)b0;
      pa.W1[tid * 8 + j] = (short)b1;
    }
  } else {
    int tid = (blockIdx.x - 13) * 256 + t;
    if (tid < 5 * 960){
      int L = tid & 63;
      int ct = (tid >> 6) % 15;
      int lay = tid / 960;
      const float* w = pa.fw[lay];
      int ncol = (lay == 4) ? 22 : D;
      int c = ct / 5, tt = ct % 5;
      int nn = tt * 16 + (L & 15);
      int kb = c * 32 + (L >> 4) * 8;
      #pragma unroll
      for (int j = 0; j < 8; j++){
        int k = kb + j;
        float v = (k < D && nn < ncol) ? w[k * ncol + nn] : 0.f;
        unsigned short b0 = bf16r(v);
        float r1 = v - bf16f(b0);
        unsigned short b1 = bf16r(r1);
        pa.F0[tid * 8 + j] = (short)b0;
        pa.F1[tid * 8 + j] = (short)b1;
      }
    } else if (tid < 5 * 960 + 400){
      int i = tid - 5 * 960;
      int lay = i / 80, col = i % 80;
      int ncol = (lay == 4) ? 22 : D;
      pa.bpack[i] = (col < ncol) ? pa.fb[lay][col] : 0.f;
    }
  }
}

// ---------------- CSR build: binned counting sort ----------------
__global__ void k_bscan(const int* __restrict__ bhist, int* __restrict__ bbase,
                        int* __restrict__ gcur, int* __restrict__ rowptr, int N, int E){
  __shared__ int sh[256];
  int t = threadIdx.x;
  int v = bhist[t];
  sh[t] = v; __syncthreads();
  for (int o = 1; o < 256; o <<= 1){
    int u = (t >= o) ? sh[t - o] : 0;
    __syncthreads();
    sh[t] += u;
    __syncthreads();
  }
  int ex = sh[t] - v;
  bbase[t] = ex;
  gcur[t] = ex;
  if (t == 255){ bbase[256] = sh[255]; rowptr[N] = E; }
}

#define PCHUNK 4096
__global__ __launch_bounds__(256) void k_part(const int* __restrict__ src, const int* __restrict__ dst,
                                              const float* __restrict__ ew,
                                              int* __restrict__ gcur, int2* __restrict__ tmp, int E){
  __shared__ int hist[256];
  __shared__ int base[256];
  int t = threadIdx.x;
  int e0 = blockIdx.x * PCHUNK;
  int eend = min(E, e0 + PCHUNK);
  hist[t] = 0;
  __syncthreads();
  for (int e = e0 + t; e < eend; e += 256)
    atomicAdd(&hist[dst[e] >> 8], 1);
  __syncthreads();
  if (hist[t] > 0) base[t] = atomicAdd(&gcur[t], hist[t]);
  hist[t] = 0;
  __syncthreads();
  for (int e = e0 + t; e < eend; e += 256){
    int d = dst[e];
    int b = d >> 8;
    int off = atomicAdd(&hist[b], 1);
    tmp[base[b] + off] = make_int2((src[e] & 0xffff) | ((d & 255) << 16), __float_as_int(ew[e]));
  }
}

__global__ __launch_bounds__(256) void k_bsort(const int2* __restrict__ tmp, const int* __restrict__ bbase,
                                               int2* __restrict__ epair, int* __restrict__ rowptr, int N){
  __shared__ int2 ebuf[CAP];
  __shared__ int lcnt[256];
  __shared__ int sc[256];
  __shared__ int lcur[256];
  int b = blockIdx.x, t = threadIdx.x;
  int s0 = bbase[b], s1 = bbase[b + 1];
  int cnt = s1 - s0;
  lcnt[t] = 0;
  __syncthreads();
  for (int j = t; j < cnt; j += 256){
    int2 e = tmp[s0 + j];
    if (j < CAP) ebuf[j] = e;
    atomicAdd(&lcnt[(e.x >> 16) & 255], 1);
  }
  __syncthreads();
  int v = lcnt[t];
  sc[t] = v; __syncthreads();
  for (int o = 1; o < 256; o <<= 1){
    int u = (t >= o) ? sc[t - o] : 0;
    __syncthreads();
    sc[t] += u;
    __syncthreads();
  }
  int ex = sc[t] - v;
  int node = (b << 8) + t;
  if (node < N) rowptr[node] = s0 + ex;
  lcur[t] = ex;
  __syncthreads();
  for (int j = t; j < cnt; j += 256){
    int2 e = (j < CAP) ? ebuf[j] : tmp[s0 + j];
    int i = (e.x >> 16) & 255;
    int p = atomicAdd(&lcur[i], 1);
    epair[s0 + p] = make_int2(e.x & 0xffff, e.y);
  }
}

// ---------------- canonicalize per-node edge order (kills CSR placement nondeterminism) ----------------
__global__ __launch_bounds__(256) void k_sortrows(const int* __restrict__ rowptr,
                                                  int2* __restrict__ epair, int n){
  const int wave = (int)((blockIdx.x * (size_t)blockDim.x + threadIdx.x) >> 6);
  const int lane = threadIdx.x & 63;
  const int l32 = lane & 31;
  const int node = wave * 2 + (lane >> 5);
  const bool valid = node < n;
  const int nd = valid ? node : (n - 1);
  const int beg = rowptr[nd];
  const int deg = rowptr[nd + 1] - beg;
  const int dmax = max(deg, __shfl_xor(deg, 32));

  if (dmax <= 32){
    unsigned long long key = ~0ull;
    if (valid && l32 < deg){
      int2 ep = epair[beg + l32];
      key = ((unsigned long long)(unsigned)ep.y << 16) | (unsigned)(ep.x & 0xffff);
    }
    #pragma unroll
    for (int k = 2; k <= 32; k <<= 1){
      #pragma unroll
      for (int j = k >> 1; j > 0; j >>= 1){
        unsigned long long pk = __shfl_xor(key, j);   // j<32: stays within the 32-lane half
        bool up    = ((l32 & k) == 0);
        bool lower = ((l32 & j) == 0);
        unsigned long long mn = key < pk ? key : pk;
        unsigned long long mx = key < pk ? pk : key;
        key = (lower == up) ? mn : mx;
      }
    }
    if (valid && l32 < deg)
      epair[beg + l32] = make_int2((int)(key & 0xffff), (int)(unsigned)(key >> 16));
  } else {
    for (int h = 0; h < 2; h++){
      int begh = __shfl(beg, h << 5);
      int degh = __shfl(deg, h << 5);
      int vh   = __shfl((int)valid, h << 5);
      if (!vh || degh <= 0) continue;                 // wave-uniform
      int dcap = min(degh, 64);
      unsigned long long key = ~0ull;
      if (lane < dcap){
        int2 ep = epair[begh + lane];
        key = ((unsigned long long)(unsigned)ep.y << 16) | (unsigned)(ep.x & 0xffff);
      }
      #pragma unroll
      for (int k = 2; k <= 64; k <<= 1){
        #pragma unroll
        for (int j = k >> 1; j > 0; j >>= 1){
          unsigned long long pk = __shfl_xor(key, j);
          bool up    = ((lane & k) == 0);
          bool lower = ((lane & j) == 0);
          unsigned long long mn = key < pk ? key : pk;
          unsigned long long mx = key < pk ? pk : key;
          key = (lower == up) ? mn : mx;
        }
      }
      if (lane < dcap)
        epair[begh + lane] = make_int2((int)(key & 0xffff), (int)(unsigned)(key >> 16));
    }
  }
}

// ---------------- GAT GEMM via 2-term bf16 MFMA; optional fused BN on input ----------------
// Output layout: Y[n][64] (256B aligned rows, cols 0..63) + Yt[n] = {y64, y65, a_src, a_dst}.
template<bool BN_IN>
__global__ __launch_bounds__(256) void k_mm(const float* __restrict__ X, const float4* __restrict__ Xt,
    const short* __restrict__ W0, const short* __restrict__ W1,
    const float* __restrict__ att_s, const float* __restrict__ att_d,
    const float* __restrict__ bn,
    float* __restrict__ Y, float4* __restrict__ Yt, int n){
  const int wv = threadIdx.x >> 6, L = threadIdx.x & 63;
  const int quad = L >> 4, m = L & 15;
  const int row0 = blockIdx.x * 64 + wv * 16;
  const int lrow = min(row0 + m, n - 1);
  f4v acc[5];
  #pragma unroll
  for (int t = 0; t < 5; t++) acc[t] = (f4v){0.f,0.f,0.f,0.f};

  #pragma unroll
  for (int c = 0; c < 3; c++){
    float xv[8];
    if (c < 2){
      if (BN_IN){
        const float* hr = X + (size_t)lrow * D + c * 32 + quad * 8;
        #pragma unroll
        for (int j = 0; j < 8; j += 2){
          float2 hv = *(const float2*)(hr + j);
          int col = c * 32 + quad * 8 + j;
          xv[j]     = hv.x * bn[col]     + bn[D + col];
          xv[j + 1] = hv.y * bn[col + 1] + bn[D + col + 1];
        }
      } else {
        const float* xr = X + (size_t)lrow * YR;
        float4 p0 = *(const float4*)&xr[c * 32 + quad * 8];
        float4 p1 = *(const float4*)&xr[c * 32 + quad * 8 + 4];
        xv[0] = p0.x; xv[1] = p0.y; xv[2] = p0.z; xv[3] = p0.w;
        xv[4] = p1.x; xv[5] = p1.y; xv[6] = p1.z; xv[7] = p1.w;
      }
    } else {
      #pragma unroll
      for (int j = 0; j < 8; j++) xv[j] = 0.f;
      if (quad == 0){
        if (BN_IN){
          float2 hv = *(const float2*)(X + (size_t)lrow * D + 64);
          xv[0] = hv.x * bn[64] + bn[D + 64];
          xv[1] = hv.y * bn[65] + bn[D + 65];
        } else {
          float4 t = Xt[lrow];
          xv[0] = t.x; xv[1] = t.y;
        }
      }
    }
    s8v a0, a1;
    split8d(xv, a0, a1);
    const short* b0p = W0 + (c * 5) * 512 + L * 8;
    const short* b1p = W1 + (c * 5) * 512 + L * 8;
    #pragma unroll
    for (int t = 0; t < 5; t++){
      s8v b0v = *(const s8v*)(b0p + t * 512);
      s8v b1v = *(const s8v*)(b1p + t * 512);
      MM4(acc[t], a0, a1, b0v, b1v)
    }
  }

  float ps[4] = {0.f,0.f,0.f,0.f}, pd[4] = {0.f,0.f,0.f,0.f};
  #pragma unroll
  for (int t = 0; t < 5; t++){
    int col = t * 16 + m;
    float as_v = 0.f, ad_v = 0.f;
    if (col < D){ as_v = att_s[col]; ad_v = att_d[col]; }
    #pragma unroll
    for (int r = 0; r < 4; r++){
      ps[r] += acc[t][r] * as_v;
      pd[r] += acc[t][r] * ad_v;
    }
  }
  // main cols 0..63
  #pragma unroll
  for (int r = 0; r < 4; r++){
    int rw = row0 + quad * 4 + r;
    if (rw < n){
      float* yr = Y + (size_t)rw * YR;
      #pragma unroll
      for (int t = 0; t < 4; t++) yr[t * 16 + m] = acc[t][r];
    }
  }
  // col 65 lives in lane m=1; pull into m=0 (wave-uniform shuffle)
  float c65[4];
  #pragma unroll
  for (int r = 0; r < 4; r++) c65[r] = __shfl_down(acc[4][r], 1);
  #pragma unroll
  for (int o = 1; o <= 8; o <<= 1){
    #pragma unroll
    for (int r = 0; r < 4; r++){
      ps[r] += __shfl_xor(ps[r], o);
      pd[r] += __shfl_xor(pd[r], o);
    }
  }
  if (m == 0){
    #pragma unroll
    for (int r = 0; r < 4; r++){
      int rw = row0 + quad * 4 + r;
      if (rw < n) Yt[rw] = make_float4(acc[4][r], c65[r], ps[r], pd[r]);
    }
  }
}

// ---------------- Fused 5-layer FC head: 32-row blocks, t-split wave pairs, 2-term MFMA ----------------
#define FST 84
__global__ __launch_bounds__(256) void k_fcmm(const float* __restrict__ X, const float4* __restrict__ Xt,
    const short* __restrict__ W0, const short* __restrict__ W1,
    const float* __restrict__ bpack, float* __restrict__ out, int n){
  __shared__ __align__(16) float xs[2][16][FST];
  const int wv = threadIdx.x >> 6, L = threadIdx.x & 63;
  const int quad = L >> 4, m = L & 15;
  const int rg = wv >> 1, th = wv & 1;
  const int row0 = blockIdx.x * 32 + rg * 16;
  const int lrow = min(row0 + m, n - 1);
  const float* xr = X + (size_t)lrow * YR;

  for (int l = 0; l < 5; l++){
    const int t0 = (l == 4) ? th : (th ? 3 : 0);
    const int nt = (l == 4) ? 1  : (th ? 2 : 3);
    f4v acc[3];
    #pragma unroll
    for (int t = 0; t < 3; t++) acc[t] = (f4v){0.f,0.f,0.f,0.f};
    #pragma unroll
    for (int c = 0; c < 3; c++){
      float xv[8];
      if (l == 0){
        if (c < 2){
          float4 p0 = *(const float4*)&xr[c * 32 + quad * 8];
          float4 p1 = *(const float4*)&xr[c * 32 + quad * 8 + 4];
          xv[0] = p0.x; xv[1] = p0.y; xv[2] = p0.z; xv[3] = p0.w;
          xv[4] = p1.x; xv[5] = p1.y; xv[6] = p1.z; xv[7] = p1.w;
        } else {
          #pragma unroll
          for (int j = 0; j < 8; j++) xv[j] = 0.f;
          if (quad == 0){
            float4 t = Xt[lrow];
            xv[0] = t.x; xv[1] = t.y;
          }
        }
      } else {
        if (c == 2 && quad >= 2){
          #pragma unroll
          for (int j = 0; j < 8; j++) xv[j] = 0.f;
        } else {
          float4 p0 = *(const float4*)&xs[rg][m][c * 32 + quad * 8];
          float4 p1 = *(const float4*)&xs[rg][m][c * 32 + quad * 8 + 4];
          xv[0] = p0.x; xv[1] = p0.y; xv[2] = p0.z; xv[3] = p0.w;
          xv[4] = p1.x; xv[5] = p1.y; xv[6] = p1.z; xv[7] = p1.w;
        }
      }
      s8v a0, a1;
      split8d(xv, a0, a1);
      const short* b0p = W0 + ((l * 3 + c) * 5 + t0) * 512 + L * 8;
      const short* b1p = W1 + ((l * 3 + c) * 5 + t0) * 512 + L * 8;
      for (int t = 0; t < nt; t++){
        s8v b0v = *(const s8v*)(b0p + t * 512);
        s8v b1v = *(const s8v*)(b1p + t * 512);
        MM4(acc[t], a0, a1, b0v, b1v)
      }
    }
    if (l < 4){
      __syncthreads();
      for (int t = 0; t < nt; t++){
        int col = (t0 + t) * 16 + m;
        float bv = bpack[l * 80 + col];
        #pragma unroll
        for (int r = 0; r < 4; r++){
          float v = acc[t][r] + bv;
          xs[rg][quad * 4 + r][col] = v > 0.f ? v : 0.f;
        }
      }
      __syncthreads();
    } else {
      int col = t0 * 16 + m;
      #pragma unroll
      for (int r = 0; r < 4; r++){
        int rw = row0 + quad * 4 + r;
        if (col < 22 && rw < n) out[(size_t)rw * 22 + col] = acc[0][r] + bpack[4 * 80 + col];
      }
    }
  }
}

// ---------------- GAT softmax + aggregate ----------------
// Phase 2: loads staged into explicit float4 temps (load loop, then FMA loop) under the SAME
// per-lane predicates -- bit-identical numerics, but all 16 global_load_dwordx4 issue before
// the first dependent FMA (R2 counters: VGPR=36 -> compiler had serialized the gather).
// Safe now: the pipeline upstream is bit-deterministic, so replays cannot diverge.
__global__ __launch_bounds__(256) void k_agg(const float* __restrict__ y, const float4* __restrict__ yt,
                                             const int* __restrict__ rowptr, const int2* __restrict__ epair,
                                             const float* __restrict__ misc, int cidx,
                                             const float* __restrict__ bias,
                                             float* __restrict__ xout, float4* __restrict__ xt, int n){
  const int wave = (int)((blockIdx.x * (size_t)blockDim.x + threadIdx.x) >> 6);
  const int lane = threadIdx.x & 63;
  const int half = lane >> 5, l32 = lane & 31;
  const int node = wave * 2 + half;
  const bool valid = node < n;
  const int nd = valid ? node : (n - 1);
  const int beg = rowptr[nd];
  const int deg = rowptr[nd + 1] - beg;
  const float ce  = misc[2 * D + cidx];
  const float adn = yt[nd].w;          // wave-uniform per half -> broadcast load
  const int dmax = max(deg, __shfl_xor(deg, 32));

  const int g = l32 >> 2, q = l32 & 3;
  float4 acc0 = make_float4(0.f,0.f,0.f,0.f);   // cols  0+4q
  float4 acc1 = make_float4(0.f,0.f,0.f,0.f);   // cols 16+4q
  float4 acc2 = make_float4(0.f,0.f,0.f,0.f);   // cols 32+4q
  float4 acc3 = make_float4(0.f,0.f,0.f,0.f);   // cols 48+4q
  float2 tacc = make_float2(0.f,0.f);           // cols 64,65 (per-lane, phase 1)

  if (dmax <= 32){
    // ---- phase 1: per-lane coef (one edge per lane); yt gather carries tail + a_src ----
    int s = 0; float coef = 0.f;
    float al = -INFINITY;
    float4 ytv = make_float4(0.f,0.f,0.f,0.f);
    if (l32 < deg){
      int2 ep = epair[beg + l32];
      s = ep.x;
      ytv = yt[s];
      al = lrelu(ytv.z + adn + ce * __int_as_float(ep.y));
    }
    float mx = al;
    #pragma unroll
    for (int o = 16; o; o >>= 1) mx = fmaxf(mx, __shfl_xor(mx, o));
    float ex = (l32 < deg) ? __expf(al - mx) : 0.f;
    float sum = ex;
    #pragma unroll
    for (int o = 16; o; o >>= 1) sum += __shfl_xor(sum, o);
    float inv = 1.f / (sum + 1e-16f);
    coef = ex * inv;
    tacc.x = coef * ytv.x;
    tacc.y = coef * ytv.y;

    // ---- hoist ALL shuffles: 4 edge-groups worth of (src, coef) per lane ----
    int   stv[4];
    float ctv[4];
    #pragma unroll
    for (int i = 0; i < 4; i++){
      int lsrc = (lane & 32) | (8 * i + g);
      stv[i] = __shfl(s,    lsrc);
      ctv[i] = __shfl(coef, lsrc);
    }
    // ---- staged gather: loads land in temps before any FMA (same per-lane predicate) ----
    float4 v0[4], v1[4], v2[4], v3[4];
    #pragma unroll
    for (int i = 0; i < 4; i++){
      if (8 * i + g < deg){
        const float* row = y + (size_t)stv[i] * YR;
        v0[i] = *(const float4*)&row[      4 * q];
        v1[i] = *(const float4*)&row[16 + 4 * q];
        v2[i] = *(const float4*)&row[32 + 4 * q];
        v3[i] = *(const float4*)&row[48 + 4 * q];
      }
    }
    #pragma unroll
    for (int i = 0; i < 4; i++){
      if (8 * i + g < deg){
        fma4(acc0, ctv[i], v0[i]);
        fma4(acc1, ctv[i], v1[i]);
        fma4(acc2, ctv[i], v2[i]);
        fma4(acc3, ctv[i], v3[i]);
      }
    }
  } else {
    // ---- rare path: deg > 32 (Poisson(20) tail) ----
    float mx = -INFINITY;
    for (int j0 = 0; j0 < dmax; j0 += 32){
      int j = j0 + l32;
      if (j < deg){
        int2 ep = epair[beg + j];
        mx = fmaxf(mx, lrelu(yt[ep.x].z + adn + ce * __int_as_float(ep.y)));
      }
    }
    #pragma unroll
    for (int o = 16; o; o >>= 1) mx = fmaxf(mx, __shfl_xor(mx, o));
    float sum = 0.f;
    for (int j0 = 0; j0 < dmax; j0 += 32){
      int j = j0 + l32;
      if (j < deg){
        int2 ep = epair[beg + j];
        sum += __expf(lrelu(yt[ep.x].z + adn + ce * __int_as_float(ep.y)) - mx);
      }
    }
    #pragma unroll
    for (int o = 16; o; o >>= 1) sum += __shfl_xor(sum, o);
    float inv = 1.f / (sum + 1e-16f);

    for (int j0 = 0; j0 < dmax; j0 += 32){
      int cs = 0; float cc = 0.f;
      int j = j0 + l32;
      if (j < deg){
        int2 ep = epair[beg + j];
        cs = ep.x;
        float4 yv = yt[cs];
        cc = __expf(lrelu(yv.z + adn + ce * __int_as_float(ep.y)) - mx) * inv;
        tacc.x += cc * yv.x;
        tacc.y += cc * yv.y;
      }
      int   stv[4];
      float ctv[4];
      #pragma unroll
      for (int i = 0; i < 4; i++){
        int lsrc = (lane & 32) | (8 * i + g);
        stv[i] = __shfl(cs, lsrc);
        ctv[i] = __shfl(cc, lsrc);
      }
      int cmax = min(32, dmax - j0);
      float4 v0[4], v1[4], v2[4], v3[4];
      #pragma unroll
      for (int i = 0; i < 4; i++){
        int e = 8 * i + g;
        if (j0 + e < deg && e < cmax){
          const float* row = y + (size_t)stv[i] * YR;
          v0[i] = *(const float4*)&row[      4 * q];
          v1[i] = *(const float4*)&row[16 + 4 * q];
          v2[i] = *(const float4*)&row[32 + 4 * q];
          v3[i] = *(const float4*)&row[48 + 4 * q];
        }
      }
      #pragma unroll
      for (int i = 0; i < 4; i++){
        int e = 8 * i + g;
        if (j0 + e < deg && e < cmax){
          fma4(acc0, ctv[i], v0[i]);
          fma4(acc1, ctv[i], v1[i]);
          fma4(acc2, ctv[i], v2[i]);
          fma4(acc3, ctv[i], v3[i]);
        }
      }
    }
  }

  // tail reduce: contributions are per-lane (all 32), fold bits 0,1 first
  tacc.x += __shfl_xor(tacc.x, 1); tacc.y += __shfl_xor(tacc.y, 1);
  tacc.x += __shfl_xor(tacc.x, 2); tacc.y += __shfl_xor(tacc.y, 2);
  // reduce over the 8 edge-groups (lane bits 2,3,4 within the half)
  #pragma unroll
  for (int o = 4; o <= 16; o <<= 1){
    acc0.x += __shfl_xor(acc0.x, o); acc0.y += __shfl_xor(acc0.y, o);
    acc0.z += __shfl_xor(acc0.z, o); acc0.w += __shfl_xor(acc0.w, o);
    acc1.x += __shfl_xor(acc1.x, o); acc1.y += __shfl_xor(acc1.y, o);
    acc1.z += __shfl_xor(acc1.z, o); acc1.w += __shfl_xor(acc1.w, o);
    acc2.x += __shfl_xor(acc2.x, o); acc2.y += __shfl_xor(acc2.y, o);
    acc2.z += __shfl_xor(acc2.z, o); acc2.w += __shfl_xor(acc2.w, o);
    acc3.x += __shfl_xor(acc3.x, o); acc3.y += __shfl_xor(acc3.y, o);
    acc3.z += __shfl_xor(acc3.z, o); acc3.w += __shfl_xor(acc3.w, o);
    tacc.x += __shfl_xor(tacc.x, o); tacc.y += __shfl_xor(tacc.y, o);
  }
  if (valid){
    float* orow = xout + (size_t)node * YR;
    if (l32 < 4){
      int c0 = 4 * l32;
      float4 v;
      v.x = acc0.x + bias[c0+0]; v.x = v.x > 0.f ? v.x : 0.f;
      v.y = acc0.y + bias[c0+1]; v.y = v.y > 0.f ? v.y : 0.f;
      v.z = acc0.z + bias[c0+2]; v.z = v.z > 0.f ? v.z : 0.f;
      v.w = acc0.w + bias[c0+3]; v.w = v.w > 0.f ? v.w : 0.f;
      *(float4*)&orow[c0] = v;
      v.x = acc1.x + bias[16+c0+0]; v.x = v.x > 0.f ? v.x : 0.f;
      v.y = acc1.y + bias[16+c0+1]; v.y = v.y > 0.f ? v.y : 0.f;
      v.z = acc1.z + bias[16+c0+2]; v.z = v.z > 0.f ? v.z : 0.f;
      v.w = acc1.w + bias[16+c0+3]; v.w = v.w > 0.f ? v.w : 0.f;
      *(float4*)&orow[16 + c0] = v;
      v.x = acc2.x + bias[32+c0+0]; v.x = v.x > 0.f ? v.x : 0.f;
      v.y = acc2.y + bias[32+c0+1]; v.y = v.y > 0.f ? v.y : 0.f;
      v.z = acc2.z + bias[32+c0+2]; v.z = v.z > 0.f ? v.z : 0.f;
      v.w = acc2.w + bias[32+c0+3]; v.w = v.w > 0.f ? v.w : 0.f;
      *(float4*)&orow[32 + c0] = v;
      v.x = acc3.x + bias[48+c0+0]; v.x = v.x > 0.f ? v.x : 0.f;
      v.y = acc3.y + bias[48+c0+1]; v.y = v.y > 0.f ? v.y : 0.f;
      v.z = acc3.z + bias[48+c0+2]; v.z = v.z > 0.f ? v.z : 0.f;
      v.w = acc3.w + bias[48+c0+3]; v.w = v.w > 0.f ? v.w : 0.f;
      *(float4*)&orow[48 + c0] = v;
    }
    if (l32 == 0){
      float tx = tacc.x + bias[64]; tx = tx > 0.f ? tx : 0.f;
      float ty = tacc.y + bias[65]; ty = ty > 0.f ? ty : 0.f;
      xt[node] = make_float4(tx, ty, 0.f, 0.f);
    }
  }
}

// ---------------- launch ----------------
extern "C" void kernel_launch(void* const* d_in, const int* in_sizes, int n_in,
                              void* d_out, int out_size, void* d_ws, size_t ws_size,
                              hipStream_t stream){
  const float* h     = (const float*)d_in[0];
  const int*   ei    = (const int*)  d_in[1];
  const float* ew    = (const float*)d_in[2];
  const float* gamma = (const float*)d_in[3];
  const float* beta  = (const float*)d_in[4];
  const float *Wl[3], *bl[3], *asl[3], *adl[3], *Wel[3], *ael[3];
  int idx = 5;
  for (int l = 0; l < 3; l++){
    Wl[l]  = (const float*)d_in[idx++];
    bl[l]  = (const float*)d_in[idx++];
    asl[l] = (const float*)d_in[idx++];
    adl[l] = (const float*)d_in[idx++];
    Wel[l] = (const float*)d_in[idx++];
    ael[l] = (const float*)d_in[idx++];
  }
  const float *fw[5], *fb[5];
  for (int l = 0; l < 5; l++){ fw[l] = (const float*)d_in[idx++]; fb[l] = (const float*)d_in[idx++]; }

  int N = in_sizes[0] / D;
  int E = in_sizes[1] / 2;
  const int* src  = ei;
  const int* dstp = ei + E;

  char* base = (char*)d_ws;
  size_t o = 0;
  auto alloc = [&](size_t b){ size_t r = o; o += (b + 255) & ~(size_t)255; return r; };
  float*  bufA   = (float*)(base + alloc((size_t)N * YR * 4));
  float*  bufB   = (float*)(base + alloc((size_t)N * YR * 4));
  float4* tA     = (float4*)(base + alloc((size_t)N * 16));
  float4* tB     = (float4*)(base + alloc((size_t)N * 16));
  float*  misc   = (float*)(base + alloc(512 * 4));
  float*  partials = (float*)(base + alloc(2 * D * 256 * 4));   // [col][256] col-major
  int*    rowptr = (int*)  (base + alloc((size_t)(N + 1) * 4));
  int*    bhist  = (int*)  (base + alloc(256 * 4));
  int*    bbase  = (int*)  (base + alloc(257 * 4));
  int*    gcur   = (int*)  (base + alloc(256 * 4));
  int2*   epair  = (int2*) (base + alloc((size_t)E * 8));
  short*  W0p    = (short*)(base + alloc(3 * 7680 * 2));
  short*  W1p    = (short*)(base + alloc(3 * 7680 * 2));
  short*  FW0p   = (short*)(base + alloc(5 * 7680 * 2));
  short*  FW1p   = (short*)(base + alloc(5 * 7680 * 2));
  float*  bpack  = (float*)(base + alloc(400 * 4));
  int2*   tmp    = (int2*)bufB;   // alias: bufB (12.8 MB) unused until first k_mm; E*8 = 8 MB fits

  hipMemsetAsync(bhist, 0, 256 * 4, stream);   // partials need no init (fully written)

  k_stats_hist<<<512, 256, 0, stream>>>(h, dstp, partials, bhist, N, E);

  PrepArgs pa;
  pa.part = partials; pa.gamma = gamma; pa.beta = beta;
  for (int l = 0; l < 3; l++){ pa.We[l] = Wel[l]; pa.ae[l] = ael[l]; pa.gw[l] = Wl[l]; }
  for (int l = 0; l < 5; l++){ pa.fw[l] = fw[l]; pa.fb[l] = fb[l]; }
  pa.misc = misc; pa.W0 = W0p; pa.W1 = W1p;
  pa.F0 = FW0p; pa.F1 = FW1p; pa.bpack = bpack; pa.n = N;
  k_prep<<<34, 256, 0, stream>>>(pa);

  int NB = (N + 255) >> 8;
  k_bscan<<<1, 256, 0, stream>>>(bhist, bbase, gcur, rowptr, N, E);
  k_part<<<(E + PCHUNK - 1) / PCHUNK, 256, 0, stream>>>(src, dstp, ew, gcur, tmp, E);
  k_bsort<<<NB, 256, 0, stream>>>(tmp, bbase, epair, rowptr, N);

  int gb = (N + 63) / 64;
  int ab = (N + 7) / 8;   // 2 nodes per wave, 4 waves per block

  k_sortrows<<<ab, 256, 0, stream>>>(rowptr, epair, N);   // canonical edge order

  k_mm<true ><<<gb, 256, 0, stream>>>(h,    nullptr, W0p + 0 * 7680, W1p + 0 * 7680,
                                      asl[0], adl[0], misc, bufB, tB, N);
  k_agg<<<ab, 256, 0, stream>>>(bufB, tB, rowptr, epair, misc, 0, bl[0], bufA, tA, N);
  k_mm<false><<<gb, 256, 0, stream>>>(bufA, tA, W0p + 1 * 7680, W1p + 1 * 7680,
                                      asl[1], adl[1], misc, bufB, tB, N);
  k_agg<<<ab, 256, 0, stream>>>(bufB, tB, rowptr, epair, misc, 1, bl[1], bufA, tA, N);
  k_mm<false><<<gb, 256, 0, stream>>>(bufA, tA, W0p + 2 * 7680, W1p + 2 * 7680,
                                      asl[2], adl[2], misc, bufB, tB, N);
  k_agg<<<ab, 256, 0, stream>>>(bufB, tB, rowptr, epair, misc, 2, bl[2], bufA, tA, N);

  int gb2 = (N + 31) / 32;
  k_fcmm<<<gb2, 256, 0, stream>>>(bufA, tA, FW0p, FW1p, bpack, (float*)d_out, N);
}

// Round 9
// 415.543 us; speedup vs baseline: 1.0286x; 1.0286x over previous
//
#include <hip/hip_runtime.h>
#include <math.h>

#define D 66
#define YR 64                 // main row stride (floats): 256B rows, 64B-segment aligned
#define NEG_SLOPE 0.2f
#define CAP 6144

typedef short s8v __attribute__((ext_vector_type(8)));   // 8 bf16 bit-patterns = 4 VGPRs
typedef float f4v __attribute__((ext_vector_type(4)));

__device__ __forceinline__ float lrelu(float a){ return a > 0.f ? a : NEG_SLOPE * a; }
__device__ __forceinline__ void fma4(float4& a, float s, const float4& w){
  a.x = fmaf(s, w.x, a.x); a.y = fmaf(s, w.y, a.y);
  a.z = fmaf(s, w.z, a.z); a.w = fmaf(s, w.w, a.w);
}
__device__ __forceinline__ unsigned short bf16r(float f){   // RNE f32->bf16
  unsigned u = __float_as_uint(f);
  u += 0x7FFFu + ((u >> 16) & 1u);
  return (unsigned short)(u >> 16);
}
__device__ __forceinline__ float bf16f(unsigned short b){
  return __uint_as_float(((unsigned)b) << 16);
}
// 2-term RNE split: v = a0 + a1 + r, a0 = rne16(v), r1 = v - a0 (EXACT in fp32),
// a1 = rne16(r1). |r| <= 2^-18 |v|, unbiased. Same decomposition as the W pack.
__device__ __forceinline__ void split8d(const float* p, s8v& a0, s8v& a1){
  #pragma unroll
  for (int j = 0; j < 8; j++){
    float v = p[j];
    unsigned short h0 = bf16r(v);
    float r1 = v - bf16f(h0);
    a0[j] = (short)h0;
    a1[j] = (short)bf16r(r1);
  }
}
#define MM4(acc, a0, a1, b0v, b1v)                                         \
  acc = __builtin_amdgcn_mfma_f32_16x16x32_bf16(a0, b0v, acc, 0, 0, 0);    \
  acc = __builtin_amdgcn_mfma_f32_16x16x32_bf16(a1, b0v, acc, 0, 0, 0);    \
  acc = __builtin_amdgcn_mfma_f32_16x16x32_bf16(a0, b1v, acc, 0, 0, 0);    \
  acc = __builtin_amdgcn_mfma_f32_16x16x32_bf16(a1, b1v, acc, 0, 0, 0);

// ---------------- BN stats (deterministic per-block partials) + bucket hist ----------------
__global__ __launch_bounds__(256) void k_stats_hist(const float* __restrict__ h, const int* __restrict__ dst,
                                                    float* __restrict__ partials, int* __restrict__ bhist,
                                                    int n, int E){
  int t = threadIdx.x;
  if (blockIdx.x < 256){
    __shared__ float ls[3 * 2 * D];
    int rpb = (n + 255) / 256;
    int r0 = blockIdx.x * rpb;
    int r1 = min(n, r0 + rpb);
    if (t < 3 * D){
      int c = t % D, seg = t / D;
      float s1 = 0.f, s2 = 0.f;
      for (int r = r0 + seg; r < r1; r += 3){
        float v = h[(size_t)r * D + c];
        s1 += v; s2 += v * v;
      }
      ls[seg * 2 * D + c]     = s1;   // direct store, no atomic
      ls[seg * 2 * D + D + c] = s2;
    }
    __syncthreads();
    if (t < 2 * D){
      float p = ls[t] + ls[2 * D + t] + ls[4 * D + t];   // fixed combine order
      partials[(size_t)t * 256 + blockIdx.x] = p;
    }
  } else {
    __shared__ int hh[256];
    hh[t] = 0;
    __syncthreads();
    int stride = 256 * 256;
    for (int e = (blockIdx.x - 256) * 256 + t; e < E; e += stride)
      atomicAdd(&hh[dst[e] >> 8], 1);                    // integer: value-deterministic
    __syncthreads();
    if (hh[t]) atomicAdd(&bhist[t], hh[t]);
  }
}

// ---------------- merged prep: BN finalize (fixed-order reduce) + GAT pack + FC pack ----------------
struct PrepArgs {
  const float *part, *gamma, *beta;
  const float *We[3], *ae[3];
  const float *gw[3];
  const float *fw[5], *fb[5];
  float *misc; short *W0, *W1; short *F0, *F1; float *bpack;
  int n;
};

__global__ __launch_bounds__(256) void k_prep(PrepArgs pa){
  int t = threadIdx.x;
  if (blockIdx.x == 0){
    if (t < D){
      const float4* pm = (const float4*)(pa.part + (size_t)t * 256);
      const float4* pv = (const float4*)(pa.part + (size_t)(D + t) * 256);
      float4 am = make_float4(0.f,0.f,0.f,0.f), av = make_float4(0.f,0.f,0.f,0.f);
      #pragma unroll 8
      for (int b = 0; b < 64; b++){
        float4 m4 = pm[b], v4 = pv[b];
        am.x += m4.x; am.y += m4.y; am.z += m4.z; am.w += m4.w;
        av.x += v4.x; av.y += v4.y; av.z += v4.z; av.w += v4.w;
      }
      float s1 = (am.x + am.y) + (am.z + am.w);
      float s2 = (av.x + av.y) + (av.z + av.w);
      float mean = s1 / (float)pa.n;
      float var  = s2 / (float)pa.n - mean * mean;
      float inv  = rsqrtf(var + 1e-5f);
      float sc = pa.gamma[t] * inv;
      pa.misc[t] = sc;
      pa.misc[D + t] = pa.beta[t] - mean * sc;
    } else if (t >= D && t < D + 3){
      int l = t - D;
      float c = 0.f;
      for (int d = 0; d < D; d++) c += pa.We[l][d] * pa.ae[l][d];
      pa.misc[2 * D + l] = c;
    }
  } else if (blockIdx.x <= 12){
    int tid = (blockIdx.x - 1) * 256 + t;
    if (tid >= 3 * 960) return;
    int L = tid & 63;
    int ct = (tid >> 6) % 15;
    int lay = tid / 960;
    const float* w = pa.gw[lay];
    int c = ct / 5, tt = ct % 5;
    int nn = tt * 16 + (L & 15);
    int kb = c * 32 + (L >> 4) * 8;
    #pragma unroll
    for (int j = 0; j < 8; j++){
      int k = kb + j;
      float v = (k < D && nn < D) ? w[k * D + nn] : 0.f;
      unsigned short b0 = bf16r(v);
      float r1 = v - bf16f(b0);
      unsigned short b1 = bf16r(r1);
      pa.W0[tid * 8 + j] = (short)b0;
      pa.W1[tid * 8 + j] = (short)b1;
    }
  } else {
    int tid = (blockIdx.x - 13) * 256 + t;
    if (tid < 5 * 960){
      int L = tid & 63;
      int ct = (tid >> 6) % 15;
      int lay = tid / 960;
      const float* w = pa.fw[lay];
      int ncol = (lay == 4) ? 22 : D;
      int c = ct / 5, tt = ct % 5;
      int nn = tt * 16 + (L & 15);
      int kb = c * 32 + (L >> 4) * 8;
      #pragma unroll
      for (int j = 0; j < 8; j++){
        int k = kb + j;
        float v = (k < D && nn < ncol) ? w[k * ncol + nn] : 0.f;
        unsigned short b0 = bf16r(v);
        float r1 = v - bf16f(b0);
        unsigned short b1 = bf16r(r1);
        pa.F0[tid * 8 + j] = (short)b0;
        pa.F1[tid * 8 + j] = (short)b1;
      }
    } else if (tid < 5 * 960 + 400){
      int i = tid - 5 * 960;
      int lay = i / 80, col = i % 80;
      int ncol = (lay == 4) ? 22 : D;
      pa.bpack[i] = (col < ncol) ? pa.fb[lay][col] : 0.f;
    }
  }
}

// ---------------- CSR build: binned counting sort ----------------
__global__ void k_bscan(const int* __restrict__ bhist, int* __restrict__ bbase,
                        int* __restrict__ gcur, int* __restrict__ rowptr, int N, int E){
  __shared__ int sh[256];
  int t = threadIdx.x;
  int v = bhist[t];
  sh[t] = v; __syncthreads();
  for (int o = 1; o < 256; o <<= 1){
    int u = (t >= o) ? sh[t - o] : 0;
    __syncthreads();
    sh[t] += u;
    __syncthreads();
  }
  int ex = sh[t] - v;
  bbase[t] = ex;
  gcur[t] = ex;
  if (t == 255){ bbase[256] = sh[255]; rowptr[N] = E; }
}

#define PCHUNK 4096
__global__ __launch_bounds__(256) void k_part(const int* __restrict__ src, const int* __restrict__ dst,
                                              const float* __restrict__ ew,
                                              int* __restrict__ gcur, int2* __restrict__ tmp, int E){
  __shared__ int hist[256];
  __shared__ int base[256];
  int t = threadIdx.x;
  int e0 = blockIdx.x * PCHUNK;
  int eend = min(E, e0 + PCHUNK);
  hist[t] = 0;
  __syncthreads();
  for (int e = e0 + t; e < eend; e += 256)
    atomicAdd(&hist[dst[e] >> 8], 1);
  __syncthreads();
  if (hist[t] > 0) base[t] = atomicAdd(&gcur[t], hist[t]);
  hist[t] = 0;
  __syncthreads();
  for (int e = e0 + t; e < eend; e += 256){
    int d = dst[e];
    int b = d >> 8;
    int off = atomicAdd(&hist[b], 1);
    tmp[base[b] + off] = make_int2((src[e] & 0xffff) | ((d & 255) << 16), __float_as_int(ew[e]));
  }
}

__global__ __launch_bounds__(256) void k_bsort(const int2* __restrict__ tmp, const int* __restrict__ bbase,
                                               int2* __restrict__ epair, int* __restrict__ rowptr, int N){
  __shared__ int2 ebuf[CAP];
  __shared__ int lcnt[256];
  __shared__ int sc[256];
  __shared__ int lcur[256];
  int b = blockIdx.x, t = threadIdx.x;
  int s0 = bbase[b], s1 = bbase[b + 1];
  int cnt = s1 - s0;
  lcnt[t] = 0;
  __syncthreads();
  for (int j = t; j < cnt; j += 256){
    int2 e = tmp[s0 + j];
    if (j < CAP) ebuf[j] = e;
    atomicAdd(&lcnt[(e.x >> 16) & 255], 1);
  }
  __syncthreads();
  int v = lcnt[t];
  sc[t] = v; __syncthreads();
  for (int o = 1; o < 256; o <<= 1){
    int u = (t >= o) ? sc[t - o] : 0;
    __syncthreads();
    sc[t] += u;
    __syncthreads();
  }
  int ex = sc[t] - v;
  int node = (b << 8) + t;
  if (node < N) rowptr[node] = s0 + ex;
  lcur[t] = ex;
  __syncthreads();
  for (int j = t; j < cnt; j += 256){
    int2 e = (j < CAP) ? ebuf[j] : tmp[s0 + j];
    int i = (e.x >> 16) & 255;
    int p = atomicAdd(&lcur[i], 1);
    epair[s0 + p] = make_int2(e.x & 0xffff, e.y);
  }
}

// ---------------- canonicalize per-node edge order (kills CSR placement nondeterminism) ----------------
__global__ __launch_bounds__(256) void k_sortrows(const int* __restrict__ rowptr,
                                                  int2* __restrict__ epair, int n){
  const int wave = (int)((blockIdx.x * (size_t)blockDim.x + threadIdx.x) >> 6);
  const int lane = threadIdx.x & 63;
  const int l32 = lane & 31;
  const int node = wave * 2 + (lane >> 5);
  const bool valid = node < n;
  const int nd = valid ? node : (n - 1);
  const int beg = rowptr[nd];
  const int deg = rowptr[nd + 1] - beg;
  const int dmax = max(deg, __shfl_xor(deg, 32));

  if (dmax <= 32){
    unsigned long long key = ~0ull;
    if (valid && l32 < deg){
      int2 ep = epair[beg + l32];
      key = ((unsigned long long)(unsigned)ep.y << 16) | (unsigned)(ep.x & 0xffff);
    }
    #pragma unroll
    for (int k = 2; k <= 32; k <<= 1){
      #pragma unroll
      for (int j = k >> 1; j > 0; j >>= 1){
        unsigned long long pk = __shfl_xor(key, j);   // j<32: stays within the 32-lane half
        bool up    = ((l32 & k) == 0);
        bool lower = ((l32 & j) == 0);
        unsigned long long mn = key < pk ? key : pk;
        unsigned long long mx = key < pk ? pk : key;
        key = (lower == up) ? mn : mx;
      }
    }
    if (valid && l32 < deg)
      epair[beg + l32] = make_int2((int)(key & 0xffff), (int)(unsigned)(key >> 16));
  } else {
    for (int h = 0; h < 2; h++){
      int begh = __shfl(beg, h << 5);
      int degh = __shfl(deg, h << 5);
      int vh   = __shfl((int)valid, h << 5);
      if (!vh || degh <= 0) continue;                 // wave-uniform
      int dcap = min(degh, 64);
      unsigned long long key = ~0ull;
      if (lane < dcap){
        int2 ep = epair[begh + lane];
        key = ((unsigned long long)(unsigned)ep.y << 16) | (unsigned)(ep.x & 0xffff);
      }
      #pragma unroll
      for (int k = 2; k <= 64; k <<= 1){
        #pragma unroll
        for (int j = k >> 1; j > 0; j >>= 1){
          unsigned long long pk = __shfl_xor(key, j);
          bool up    = ((lane & k) == 0);
          bool lower = ((lane & j) == 0);
          unsigned long long mn = key < pk ? key : pk;
          unsigned long long mx = key < pk ? pk : key;
          key = (lower == up) ? mn : mx;
        }
      }
      if (lane < dcap)
        epair[begh + lane] = make_int2((int)(key & 0xffff), (int)(unsigned)(key >> 16));
    }
  }
}

// ---------------- GAT GEMM via 2-term bf16 MFMA; optional fused BN on input ----------------
// Output layout: Y[n][64] (256B aligned rows, cols 0..63) + Yt[n] = {y64, y65, a_src, a_dst}.
template<bool BN_IN>
__global__ __launch_bounds__(256) void k_mm(const float* __restrict__ X, const float4* __restrict__ Xt,
    const short* __restrict__ W0, const short* __restrict__ W1,
    const float* __restrict__ att_s, const float* __restrict__ att_d,
    const float* __restrict__ bn,
    float* __restrict__ Y, float4* __restrict__ Yt, int n){
  const int wv = threadIdx.x >> 6, L = threadIdx.x & 63;
  const int quad = L >> 4, m = L & 15;
  const int row0 = blockIdx.x * 64 + wv * 16;
  const int lrow = min(row0 + m, n - 1);
  f4v acc[5];
  #pragma unroll
  for (int t = 0; t < 5; t++) acc[t] = (f4v){0.f,0.f,0.f,0.f};

  #pragma unroll
  for (int c = 0; c < 3; c++){
    float xv[8];
    if (c < 2){
      if (BN_IN){
        const float* hr = X + (size_t)lrow * D + c * 32 + quad * 8;
        #pragma unroll
        for (int j = 0; j < 8; j += 2){
          float2 hv = *(const float2*)(hr + j);
          int col = c * 32 + quad * 8 + j;
          xv[j]     = hv.x * bn[col]     + bn[D + col];
          xv[j + 1] = hv.y * bn[col + 1] + bn[D + col + 1];
        }
      } else {
        const float* xr = X + (size_t)lrow * YR;
        float4 p0 = *(const float4*)&xr[c * 32 + quad * 8];
        float4 p1 = *(const float4*)&xr[c * 32 + quad * 8 + 4];
        xv[0] = p0.x; xv[1] = p0.y; xv[2] = p0.z; xv[3] = p0.w;
        xv[4] = p1.x; xv[5] = p1.y; xv[6] = p1.z; xv[7] = p1.w;
      }
    } else {
      #pragma unroll
      for (int j = 0; j < 8; j++) xv[j] = 0.f;
      if (quad == 0){
        if (BN_IN){
          float2 hv = *(const float2*)(X + (size_t)lrow * D + 64);
          xv[0] = hv.x * bn[64] + bn[D + 64];
          xv[1] = hv.y * bn[65] + bn[D + 65];
        } else {
          float4 t = Xt[lrow];
          xv[0] = t.x; xv[1] = t.y;
        }
      }
    }
    s8v a0, a1;
    split8d(xv, a0, a1);
    const short* b0p = W0 + (c * 5) * 512 + L * 8;
    const short* b1p = W1 + (c * 5) * 512 + L * 8;
    #pragma unroll
    for (int t = 0; t < 5; t++){
      s8v b0v = *(const s8v*)(b0p + t * 512);
      s8v b1v = *(const s8v*)(b1p + t * 512);
      MM4(acc[t], a0, a1, b0v, b1v)
    }
  }

  float ps[4] = {0.f,0.f,0.f,0.f}, pd[4] = {0.f,0.f,0.f,0.f};
  #pragma unroll
  for (int t = 0; t < 5; t++){
    int col = t * 16 + m;
    float as_v = 0.f, ad_v = 0.f;
    if (col < D){ as_v = att_s[col]; ad_v = att_d[col]; }
    #pragma unroll
    for (int r = 0; r < 4; r++){
      ps[r] += acc[t][r] * as_v;
      pd[r] += acc[t][r] * ad_v;
    }
  }
  // main cols 0..63
  #pragma unroll
  for (int r = 0; r < 4; r++){
    int rw = row0 + quad * 4 + r;
    if (rw < n){
      float* yr = Y + (size_t)rw * YR;
      #pragma unroll
      for (int t = 0; t < 4; t++) yr[t * 16 + m] = acc[t][r];
    }
  }
  // col 65 lives in lane m=1; pull into m=0 (wave-uniform shuffle)
  float c65[4];
  #pragma unroll
  for (int r = 0; r < 4; r++) c65[r] = __shfl_down(acc[4][r], 1);
  #pragma unroll
  for (int o = 1; o <= 8; o <<= 1){
    #pragma unroll
    for (int r = 0; r < 4; r++){
      ps[r] += __shfl_xor(ps[r], o);
      pd[r] += __shfl_xor(pd[r], o);
    }
  }
  if (m == 0){
    #pragma unroll
    for (int r = 0; r < 4; r++){
      int rw = row0 + quad * 4 + r;
      if (rw < n) Yt[rw] = make_float4(acc[4][r], c65[r], ps[r], pd[r]);
    }
  }
}

// ---------------- Fused 5-layer FC head: 32-row blocks, t-split wave pairs, 2-term MFMA ----------------
// Activations stored in LDS PRE-SPLIT as bf16 (a0,a1) pairs: the producing wave applies the
// identical RNE 2-term decomposition once at write time; readers ds_read_b128 the s8v
// fragments directly. Bit-identical numerics to the read-side split (same RNE ops on same
// post-ReLU f32 values), but conversion VALU is 1x (writer) instead of 2x (both th waves),
// and LDS read bytes are halved. Stride 88 shorts = 176B: 16B-aligned, 2-way-bank-free.
#define FSH 88
__global__ __launch_bounds__(256) void k_fcmm(const float* __restrict__ X, const float4* __restrict__ Xt,
    const short* __restrict__ W0, const short* __restrict__ W1,
    const float* __restrict__ bpack, float* __restrict__ out, int n){
  __shared__ __align__(16) short xa0[2][16][FSH];
  __shared__ __align__(16) short xa1[2][16][FSH];
  const int wv = threadIdx.x >> 6, L = threadIdx.x & 63;
  const int quad = L >> 4, m = L & 15;
  const int rg = wv >> 1, th = wv & 1;
  const int row0 = blockIdx.x * 32 + rg * 16;
  const int lrow = min(row0 + m, n - 1);
  const float* xr = X + (size_t)lrow * YR;

  for (int l = 0; l < 5; l++){
    const int t0 = (l == 4) ? th : (th ? 3 : 0);
    const int nt = (l == 4) ? 1  : (th ? 2 : 3);
    f4v acc[3];
    #pragma unroll
    for (int t = 0; t < 3; t++) acc[t] = (f4v){0.f,0.f,0.f,0.f};
    #pragma unroll
    for (int c = 0; c < 3; c++){
      s8v a0, a1;
      if (l == 0){
        float xv[8];
        if (c < 2){
          float4 p0 = *(const float4*)&xr[c * 32 + quad * 8];
          float4 p1 = *(const float4*)&xr[c * 32 + quad * 8 + 4];
          xv[0] = p0.x; xv[1] = p0.y; xv[2] = p0.z; xv[3] = p0.w;
          xv[4] = p1.x; xv[5] = p1.y; xv[6] = p1.z; xv[7] = p1.w;
        } else {
          #pragma unroll
          for (int j = 0; j < 8; j++) xv[j] = 0.f;
          if (quad == 0){
            float4 t = Xt[lrow];
            xv[0] = t.x; xv[1] = t.y;
          }
        }
        split8d(xv, a0, a1);
      } else {
        if (c == 2 && quad >= 2){
          a0 = (s8v){0,0,0,0,0,0,0,0};
          a1 = (s8v){0,0,0,0,0,0,0,0};
        } else {
          a0 = *(const s8v*)&xa0[rg][m][c * 32 + quad * 8];
          a1 = *(const s8v*)&xa1[rg][m][c * 32 + quad * 8];
        }
      }
      const short* b0p = W0 + ((l * 3 + c) * 5 + t0) * 512 + L * 8;
      const short* b1p = W1 + ((l * 3 + c) * 5 + t0) * 512 + L * 8;
      for (int t = 0; t < nt; t++){
        s8v b0v = *(const s8v*)(b0p + t * 512);
        s8v b1v = *(const s8v*)(b1p + t * 512);
        MM4(acc[t], a0, a1, b0v, b1v)
      }
    }
    if (l < 4){
      __syncthreads();
      for (int t = 0; t < nt; t++){
        int col = (t0 + t) * 16 + m;
        float bv = bpack[l * 80 + col];
        #pragma unroll
        for (int r = 0; r < 4; r++){
          float v = acc[t][r] + bv;
          v = v > 0.f ? v : 0.f;
          unsigned short b0 = bf16r(v);
          float r1 = v - bf16f(b0);
          xa0[rg][quad * 4 + r][col] = (short)b0;
          xa1[rg][quad * 4 + r][col] = (short)bf16r(r1);
        }
      }
      __syncthreads();
    } else {
      int col = t0 * 16 + m;
      #pragma unroll
      for (int r = 0; r < 4; r++){
        int rw = row0 + quad * 4 + r;
        if (col < 22 && rw < n) out[(size_t)rw * 22 + col] = acc[0][r] + bpack[4 * 80 + col];
      }
    }
  }
}

// ---------------- GAT softmax + aggregate (UNCHANGED from R8) ----------------
__global__ __launch_bounds__(256) void k_agg(const float* __restrict__ y, const float4* __restrict__ yt,
                                             const int* __restrict__ rowptr, const int2* __restrict__ epair,
                                             const float* __restrict__ misc, int cidx,
                                             const float* __restrict__ bias,
                                             float* __restrict__ xout, float4* __restrict__ xt, int n){
  const int wave = (int)((blockIdx.x * (size_t)blockDim.x + threadIdx.x) >> 6);
  const int lane = threadIdx.x & 63;
  const int half = lane >> 5, l32 = lane & 31;
  const int node = wave * 2 + half;
  const bool valid = node < n;
  const int nd = valid ? node : (n - 1);
  const int beg = rowptr[nd];
  const int deg = rowptr[nd + 1] - beg;
  const float ce  = misc[2 * D + cidx];
  const float adn = yt[nd].w;          // wave-uniform per half -> broadcast load
  const int dmax = max(deg, __shfl_xor(deg, 32));

  const int g = l32 >> 2, q = l32 & 3;
  float4 acc0 = make_float4(0.f,0.f,0.f,0.f);   // cols  0+4q
  float4 acc1 = make_float4(0.f,0.f,0.f,0.f);   // cols 16+4q
  float4 acc2 = make_float4(0.f,0.f,0.f,0.f);   // cols 32+4q
  float4 acc3 = make_float4(0.f,0.f,0.f,0.f);   // cols 48+4q
  float2 tacc = make_float2(0.f,0.f);           // cols 64,65 (per-lane, phase 1)

  if (dmax <= 32){
    // ---- phase 1: per-lane coef (one edge per lane); yt gather carries tail + a_src ----
    int s = 0; float coef = 0.f;
    float al = -INFINITY;
    float4 ytv = make_float4(0.f,0.f,0.f,0.f);
    if (l32 < deg){
      int2 ep = epair[beg + l32];
      s = ep.x;
      ytv = yt[s];
      al = lrelu(ytv.z + adn + ce * __int_as_float(ep.y));
    }
    float mx = al;
    #pragma unroll
    for (int o = 16; o; o >>= 1) mx = fmaxf(mx, __shfl_xor(mx, o));
    float ex = (l32 < deg) ? __expf(al - mx) : 0.f;
    float sum = ex;
    #pragma unroll
    for (int o = 16; o; o >>= 1) sum += __shfl_xor(sum, o);
    float inv = 1.f / (sum + 1e-16f);
    coef = ex * inv;
    tacc.x = coef * ytv.x;
    tacc.y = coef * ytv.y;

    // ---- hoist ALL shuffles: 4 edge-groups worth of (src, coef) per lane ----
    int   stv[4];
    float ctv[4];
    #pragma unroll
    for (int i = 0; i < 4; i++){
      int lsrc = (lane & 32) | (8 * i + g);
      stv[i] = __shfl(s,    lsrc);
      ctv[i] = __shfl(coef, lsrc);
    }
    // ---- staged gather: loads land in temps before any FMA (same per-lane predicate) ----
    float4 v0[4], v1[4], v2[4], v3[4];
    #pragma unroll
    for (int i = 0; i < 4; i++){
      if (8 * i + g < deg){
        const float* row = y + (size_t)stv[i] * YR;
        v0[i] = *(const float4*)&row[      4 * q];
        v1[i] = *(const float4*)&row[16 + 4 * q];
        v2[i] = *(const float4*)&row[32 + 4 * q];
        v3[i] = *(const float4*)&row[48 + 4 * q];
      }
    }
    #pragma unroll
    for (int i = 0; i < 4; i++){
      if (8 * i + g < deg){
        fma4(acc0, ctv[i], v0[i]);
        fma4(acc1, ctv[i], v1[i]);
        fma4(acc2, ctv[i], v2[i]);
        fma4(acc3, ctv[i], v3[i]);
      }
    }
  } else {
    // ---- rare path: deg > 32 (Poisson(20) tail) ----
    float mx = -INFINITY;
    for (int j0 = 0; j0 < dmax; j0 += 32){
      int j = j0 + l32;
      if (j < deg){
        int2 ep = epair[beg + j];
        mx = fmaxf(mx, lrelu(yt[ep.x].z + adn + ce * __int_as_float(ep.y)));
      }
    }
    #pragma unroll
    for (int o = 16; o; o >>= 1) mx = fmaxf(mx, __shfl_xor(mx, o));
    float sum = 0.f;
    for (int j0 = 0; j0 < dmax; j0 += 32){
      int j = j0 + l32;
      if (j < deg){
        int2 ep = epair[beg + j];
        sum += __expf(lrelu(yt[ep.x].z + adn + ce * __int_as_float(ep.y)) - mx);
      }
    }
    #pragma unroll
    for (int o = 16; o; o >>= 1) sum += __shfl_xor(sum, o);
    float inv = 1.f / (sum + 1e-16f);

    for (int j0 = 0; j0 < dmax; j0 += 32){
      int cs = 0; float cc = 0.f;
      int j = j0 + l32;
      if (j < deg){
        int2 ep = epair[beg + j];
        cs = ep.x;
        float4 yv = yt[cs];
        cc = __expf(lrelu(yv.z + adn + ce * __int_as_float(ep.y)) - mx) * inv;
        tacc.x += cc * yv.x;
        tacc.y += cc * yv.y;
      }
      int   stv[4];
      float ctv[4];
      #pragma unroll
      for (int i = 0; i < 4; i++){
        int lsrc = (lane & 32) | (8 * i + g);
        stv[i] = __shfl(cs, lsrc);
        ctv[i] = __shfl(cc, lsrc);
      }
      int cmax = min(32, dmax - j0);
      float4 v0[4], v1[4], v2[4], v3[4];
      #pragma unroll
      for (int i = 0; i < 4; i++){
        int e = 8 * i + g;
        if (j0 + e < deg && e < cmax){
          const float* row = y + (size_t)stv[i] * YR;
          v0[i] = *(const float4*)&row[      4 * q];
          v1[i] = *(const float4*)&row[16 + 4 * q];
          v2[i] = *(const float4*)&row[32 + 4 * q];
          v3[i] = *(const float4*)&row[48 + 4 * q];
        }
      }
      #pragma unroll
      for (int i = 0; i < 4; i++){
        int e = 8 * i + g;
        if (j0 + e < deg && e < cmax){
          fma4(acc0, ctv[i], v0[i]);
          fma4(acc1, ctv[i], v1[i]);
          fma4(acc2, ctv[i], v2[i]);
          fma4(acc3, ctv[i], v3[i]);
        }
      }
    }
  }

  // tail reduce: contributions are per-lane (all 32), fold bits 0,1 first
  tacc.x += __shfl_xor(tacc.x, 1); tacc.y += __shfl_xor(tacc.y, 1);
  tacc.x += __shfl_xor(tacc.x, 2); tacc.y += __shfl_xor(tacc.y, 2);
  // reduce over the 8 edge-groups (lane bits 2,3,4 within the half)
  #pragma unroll
  for (int o = 4; o <= 16; o <<= 1){
    acc0.x += __shfl_xor(acc0.x, o); acc0.y += __shfl_xor(acc0.y, o);
    acc0.z += __shfl_xor(acc0.z, o); acc0.w += __shfl_xor(acc0.w, o);
    acc1.x += __shfl_xor(acc1.x, o); acc1.y += __shfl_xor(acc1.y, o);
    acc1.z += __shfl_xor(acc1.z, o); acc1.w += __shfl_xor(acc1.w, o);
    acc2.x += __shfl_xor(acc2.x, o); acc2.y += __shfl_xor(acc2.y, o);
    acc2.z += __shfl_xor(acc2.z, o); acc2.w += __shfl_xor(acc2.w, o);
    acc3.x += __shfl_xor(acc3.x, o); acc3.y += __shfl_xor(acc3.y, o);
    acc3.z += __shfl_xor(acc3.z, o); acc3.w += __shfl_xor(acc3.w, o);
    tacc.x += __shfl_xor(tacc.x, o); tacc.y += __shfl_xor(tacc.y, o);
  }
  if (valid){
    float* orow = xout + (size_t)node * YR;
    if (l32 < 4){
      int c0 = 4 * l32;
      float4 v;
      v.x = acc0.x + bias[c0+0]; v.x = v.x > 0.f ? v.x : 0.f;
      v.y = acc0.y + bias[c0+1]; v.y = v.y > 0.f ? v.y : 0.f;
      v.z = acc0.z + bias[c0+2]; v.z = v.z > 0.f ? v.z : 0.f;
      v.w = acc0.w + bias[c0+3]; v.w = v.w > 0.f ? v.w : 0.f;
      *(float4*)&orow[c0] = v;
      v.x = acc1.x + bias[16+c0+0]; v.x = v.x > 0.f ? v.x : 0.f;
      v.y = acc1.y + bias[16+c0+1]; v.y = v.y > 0.f ? v.y : 0.f;
      v.z = acc1.z + bias[16+c0+2]; v.z = v.z > 0.f ? v.z : 0.f;
      v.w = acc1.w + bias[16+c0+3]; v.w = v.w > 0.f ? v.w : 0.f;
      *(float4*)&orow[16 + c0] = v;
      v.x = acc2.x + bias[32+c0+0]; v.x = v.x > 0.f ? v.x : 0.f;
      v.y = acc2.y + bias[32+c0+1]; v.y = v.y > 0.f ? v.y : 0.f;
      v.z = acc2.z + bias[32+c0+2]; v.z = v.z > 0.f ? v.z : 0.f;
      v.w = acc2.w + bias[32+c0+3]; v.w = v.w > 0.f ? v.w : 0.f;
      *(float4*)&orow[32 + c0] = v;
      v.x = acc3.x + bias[48+c0+0]; v.x = v.x > 0.f ? v.x : 0.f;
      v.y = acc3.y + bias[48+c0+1]; v.y = v.y > 0.f ? v.y : 0.f;
      v.z = acc3.z + bias[48+c0+2]; v.z = v.z > 0.f ? v.z : 0.f;
      v.w = acc3.w + bias[48+c0+3]; v.w = v.w > 0.f ? v.w : 0.f;
      *(float4*)&orow[48 + c0] = v;
    }
    if (l32 == 0){
      float tx = tacc.x + bias[64]; tx = tx > 0.f ? tx : 0.f;
      float ty = tacc.y + bias[65]; ty = ty > 0.f ? ty : 0.f;
      xt[node] = make_float4(tx, ty, 0.f, 0.f);
    }
  }
}

// ---------------- launch ----------------
extern "C" void kernel_launch(void* const* d_in, const int* in_sizes, int n_in,
                              void* d_out, int out_size, void* d_ws, size_t ws_size,
                              hipStream_t stream){
  const float* h     = (const float*)d_in[0];
  const int*   ei    = (const int*)  d_in[1];
  const float* ew    = (const float*)d_in[2];
  const float* gamma = (const float*)d_in[3];
  const float* beta  = (const float*)d_in[4];
  const float *Wl[3], *bl[3], *asl[3], *adl[3], *Wel[3], *ael[3];
  int idx = 5;
  for (int l = 0; l < 3; l++){
    Wl[l]  = (const float*)d_in[idx++];
    bl[l]  = (const float*)d_in[idx++];
    asl[l] = (const float*)d_in[idx++];
    adl[l] = (const float*)d_in[idx++];
    Wel[l] = (const float*)d_in[idx++];
    ael[l] = (const float*)d_in[idx++];
  }
  const float *fw[5], *fb[5];
  for (int l = 0; l < 5; l++){ fw[l] = (const float*)d_in[idx++]; fb[l] = (const float*)d_in[idx++]; }

  int N = in_sizes[0] / D;
  int E = in_sizes[1] / 2;
  const int* src  = ei;
  const int* dstp = ei + E;

  char* base = (char*)d_ws;
  size_t o = 0;
  auto alloc = [&](size_t b){ size_t r = o; o += (b + 255) & ~(size_t)255; return r; };
  float*  bufA   = (float*)(base + alloc((size_t)N * YR * 4));
  float*  bufB   = (float*)(base + alloc((size_t)N * YR * 4));
  float4* tA     = (float4*)(base + alloc((size_t)N * 16));
  float4* tB     = (float4*)(base + alloc((size_t)N * 16));
  float*  misc   = (float*)(base + alloc(512 * 4));
  float*  partials = (float*)(base + alloc(2 * D * 256 * 4));   // [col][256] col-major
  int*    rowptr = (int*)  (base + alloc((size_t)(N + 1) * 4));
  int*    bhist  = (int*)  (base + alloc(256 * 4));
  int*    bbase  = (int*)  (base + alloc(257 * 4));
  int*    gcur   = (int*)  (base + alloc(256 * 4));
  int2*   epair  = (int2*) (base + alloc((size_t)E * 8));
  short*  W0p    = (short*)(base + alloc(3 * 7680 * 2));
  short*  W1p    = (short*)(base + alloc(3 * 7680 * 2));
  short*  FW0p   = (short*)(base + alloc(5 * 7680 * 2));
  short*  FW1p   = (short*)(base + alloc(5 * 7680 * 2));
  float*  bpack  = (float*)(base + alloc(400 * 4));
  int2*   tmp    = (int2*)bufB;   // alias: bufB (12.8 MB) unused until first k_mm; E*8 = 8 MB fits

  hipMemsetAsync(bhist, 0, 256 * 4, stream);   // partials need no init (fully written)

  k_stats_hist<<<512, 256, 0, stream>>>(h, dstp, partials, bhist, N, E);

  PrepArgs pa;
  pa.part = partials; pa.gamma = gamma; pa.beta = beta;
  for (int l = 0; l < 3; l++){ pa.We[l] = Wel[l]; pa.ae[l] = ael[l]; pa.gw[l] = Wl[l]; }
  for (int l = 0; l < 5; l++){ pa.fw[l] = fw[l]; pa.fb[l] = fb[l]; }
  pa.misc = misc; pa.W0 = W0p; pa.W1 = W1p;
  pa.F0 = FW0p; pa.F1 = FW1p; pa.bpack = bpack; pa.n = N;
  k_prep<<<34, 256, 0, stream>>>(pa);

  int NB = (N + 255) >> 8;
  k_bscan<<<1, 256, 0, stream>>>(bhist, bbase, gcur, rowptr, N, E);
  k_part<<<(E + PCHUNK - 1) / PCHUNK, 256, 0, stream>>>(src, dstp, ew, gcur, tmp, E);
  k_bsort<<<NB, 256, 0, stream>>>(tmp, bbase, epair, rowptr, N);

  int gb = (N + 63) / 64;
  int ab = (N + 7) / 8;   // 2 nodes per wave, 4 waves per block

  k_sortrows<<<ab, 256, 0, stream>>>(rowptr, epair, N);   // canonical edge order

  k_mm<true ><<<gb, 256, 0, stream>>>(h,    nullptr, W0p + 0 * 7680, W1p + 0 * 7680,
                                      asl[0], adl[0], misc, bufB, tB, N);
  k_agg<<<ab, 256, 0, stream>>>(bufB, tB, rowptr, epair, misc, 0, bl[0], bufA, tA, N);
  k_mm<false><<<gb, 256, 0, stream>>>(bufA, tA, W0p + 1 * 7680, W1p + 1 * 7680,
                                      asl[1], adl[1], misc, bufB, tB, N);
  k_agg<<<ab, 256, 0, stream>>>(bufB, tB, rowptr, epair, misc, 1, bl[1], bufA, tA, N);
  k_mm<false><<<gb, 256, 0, stream>>>(bufA, tA, W0p + 2 * 7680, W1p + 2 * 7680,
                                      asl[2], adl[2], misc, bufB, tB, N);
  k_agg<<<ab, 256, 0, stream>>>(bufB, tB, rowptr, epair, misc, 2, bl[2], bufA, tA, N);

  int gb2 = (N + 31) / 32;
  k_fcmm<<<gb2, 256, 0, stream>>>(bufA, tA, FW0p, FW1p, bpack, (float*)d_out, N);
}

// Round 11
// 415.481 us; speedup vs baseline: 1.0287x; 1.0001x over previous
//
#include <hip/hip_runtime.h>
#include <math.h>

#define D 66
#define YR 64                 // main row stride (floats): 256B rows, 64B-segment aligned
#define NEG_SLOPE 0.2f
#define CAP 6144

typedef short s8v __attribute__((ext_vector_type(8)));   // 8 bf16 bit-patterns = 4 VGPRs
typedef float f4v __attribute__((ext_vector_type(4)));

__device__ __forceinline__ float lrelu(float a){ return a > 0.f ? a : NEG_SLOPE * a; }
__device__ __forceinline__ void fma4(float4& a, float s, const float4& w){
  a.x = fmaf(s, w.x, a.x); a.y = fmaf(s, w.y, a.y);
  a.z = fmaf(s, w.z, a.z); a.w = fmaf(s, w.w, a.w);
}
__device__ __forceinline__ unsigned short bf16r(float f){   // RNE f32->bf16
  unsigned u = __float_as_uint(f);
  u += 0x7FFFu + ((u >> 16) & 1u);
  return (unsigned short)(u >> 16);
}
__device__ __forceinline__ float bf16f(unsigned short b){
  return __uint_as_float(((unsigned)b) << 16);
}
// 2-term RNE split: v = a0 + a1 + r, a0 = rne16(v), r1 = v - a0 (EXACT in fp32),
// a1 = rne16(r1). |r| <= 2^-18 |v|, unbiased. Same decomposition as the W pack.
__device__ __forceinline__ void split8d(const float* p, s8v& a0, s8v& a1){
  #pragma unroll
  for (int j = 0; j < 8; j++){
    float v = p[j];
    unsigned short h0 = bf16r(v);
    float r1 = v - bf16f(h0);
    a0[j] = (short)h0;
    a1[j] = (short)bf16r(r1);
  }
}
#define MM4(acc, a0, a1, b0v, b1v)                                         \
  acc = __builtin_amdgcn_mfma_f32_16x16x32_bf16(a0, b0v, acc, 0, 0, 0);    \
  acc = __builtin_amdgcn_mfma_f32_16x16x32_bf16(a1, b0v, acc, 0, 0, 0);    \
  acc = __builtin_amdgcn_mfma_f32_16x16x32_bf16(a0, b1v, acc, 0, 0, 0);    \
  acc = __builtin_amdgcn_mfma_f32_16x16x32_bf16(a1, b1v, acc, 0, 0, 0);

// ---------------- BN stats (deterministic per-block partials) + bucket hist ----------------
__global__ __launch_bounds__(256) void k_stats_hist(const float* __restrict__ h, const int* __restrict__ dst,
                                                    float* __restrict__ partials, int* __restrict__ bhist,
                                                    int n, int E){
  int t = threadIdx.x;
  if (blockIdx.x < 256){
    __shared__ float ls[3 * 2 * D];
    int rpb = (n + 255) / 256;
    int r0 = blockIdx.x * rpb;
    int r1 = min(n, r0 + rpb);
    if (t < 3 * D){
      int c = t % D, seg = t / D;
      float s1 = 0.f, s2 = 0.f;
      for (int r = r0 + seg; r < r1; r += 3){
        float v = h[(size_t)r * D + c];
        s1 += v; s2 += v * v;
      }
      ls[seg * 2 * D + c]     = s1;   // direct store, no atomic
      ls[seg * 2 * D + D + c] = s2;
    }
    __syncthreads();
    if (t < 2 * D){
      float p = ls[t] + ls[2 * D + t] + ls[4 * D + t];   // fixed combine order
      partials[(size_t)t * 256 + blockIdx.x] = p;
    }
  } else {
    __shared__ int hh[256];
    hh[t] = 0;
    __syncthreads();
    int stride = 256 * 256;
    for (int e = (blockIdx.x - 256) * 256 + t; e < E; e += stride)
      atomicAdd(&hh[dst[e] >> 8], 1);                    // integer: value-deterministic
    __syncthreads();
    if (hh[t]) atomicAdd(&bhist[t], hh[t]);
  }
}

// ---------------- merged prep: BN finalize (fixed-order reduce) + GAT pack + FC pack ----------------
struct PrepArgs {
  const float *part, *gamma, *beta;
  const float *We[3], *ae[3];
  const float *gw[3];
  const float *fw[5], *fb[5];
  float *misc; short *W0, *W1; short *F0, *F1; float *bpack;
  int n;
};

__global__ __launch_bounds__(256) void k_prep(PrepArgs pa){
  int t = threadIdx.x;
  if (blockIdx.x == 0){
    if (t < D){
      const float4* pm = (const float4*)(pa.part + (size_t)t * 256);
      const float4* pv = (const float4*)(pa.part + (size_t)(D + t) * 256);
      float4 am = make_float4(0.f,0.f,0.f,0.f), av = make_float4(0.f,0.f,0.f,0.f);
      #pragma unroll 8
      for (int b = 0; b < 64; b++){
        float4 m4 = pm[b], v4 = pv[b];
        am.x += m4.x; am.y += m4.y; am.z += m4.z; am.w += m4.w;
        av.x += v4.x; av.y += v4.y; av.z += v4.z; av.w += v4.w;
      }
      float s1 = (am.x + am.y) + (am.z + am.w);
      float s2 = (av.x + av.y) + (av.z + av.w);
      float mean = s1 / (float)pa.n;
      float var  = s2 / (float)pa.n - mean * mean;
      float inv  = rsqrtf(var + 1e-5f);
      float sc = pa.gamma[t] * inv;
      pa.misc[t] = sc;
      pa.misc[D + t] = pa.beta[t] - mean * sc;
    } else if (t >= D && t < D + 3){
      int l = t - D;
      float c = 0.f;
      for (int d = 0; d < D; d++) c += pa.We[l][d] * pa.ae[l][d];
      pa.misc[2 * D + l] = c;
    }
  } else if (blockIdx.x <= 12){
    int tid = (blockIdx.x - 1) * 256 + t;
    if (tid >= 3 * 960) return;
    int L = tid & 63;
    int ct = (tid >> 6) % 15;
    int lay = tid / 960;
    const float* w = pa.gw[lay];
    int c = ct / 5, tt = ct % 5;
    int nn = tt * 16 + (L & 15);
    int kb = c * 32 + (L >> 4) * 8;
    #pragma unroll
    for (int j = 0; j < 8; j++){
      int k = kb + j;
      float v = (k < D && nn < D) ? w[k * D + nn] : 0.f;
      unsigned short b0 = bf16r(v);
      float r1 = v - bf16f(b0);
      unsigned short b1 = bf16r(r1);
      pa.W0[tid * 8 + j] = (short)b0;
      pa.W1[tid * 8 + j] = (short)b1;
    }
  } else {
    int tid = (blockIdx.x - 13) * 256 + t;
    if (tid < 5 * 960){
      int L = tid & 63;
      int ct = (tid >> 6) % 15;
      int lay = tid / 960;
      const float* w = pa.fw[lay];
      int ncol = (lay == 4) ? 22 : D;
      int c = ct / 5, tt = ct % 5;
      int nn = tt * 16 + (L & 15);
      int kb = c * 32 + (L >> 4) * 8;
      #pragma unroll
      for (int j = 0; j < 8; j++){
        int k = kb + j;
        float v = (k < D && nn < ncol) ? w[k * ncol + nn] : 0.f;
        unsigned short b0 = bf16r(v);
        float r1 = v - bf16f(b0);
        unsigned short b1 = bf16r(r1);
        pa.F0[tid * 8 + j] = (short)b0;
        pa.F1[tid * 8 + j] = (short)b1;
      }
    } else if (tid < 5 * 960 + 400){
      int i = tid - 5 * 960;
      int lay = i / 80, col = i % 80;
      int ncol = (lay == 4) ? 22 : D;
      pa.bpack[i] = (col < ncol) ? pa.fb[lay][col] : 0.f;
    }
  }
}

// ---------------- CSR build: binned counting sort ----------------
__global__ void k_bscan(const int* __restrict__ bhist, int* __restrict__ bbase,
                        int* __restrict__ gcur, int* __restrict__ rowptr, int N, int E){
  __shared__ int sh[256];
  int t = threadIdx.x;
  int v = bhist[t];
  sh[t] = v; __syncthreads();
  for (int o = 1; o < 256; o <<= 1){
    int u = (t >= o) ? sh[t - o] : 0;
    __syncthreads();
    sh[t] += u;
    __syncthreads();
  }
  int ex = sh[t] - v;
  bbase[t] = ex;
  gcur[t] = ex;
  if (t == 255){ bbase[256] = sh[255]; rowptr[N] = E; }
}

#define PCHUNK 4096
__global__ __launch_bounds__(256) void k_part(const int* __restrict__ src, const int* __restrict__ dst,
                                              const float* __restrict__ ew,
                                              int* __restrict__ gcur, int2* __restrict__ tmp, int E){
  __shared__ int hist[256];
  __shared__ int base[256];
  int t = threadIdx.x;
  int e0 = blockIdx.x * PCHUNK;
  int eend = min(E, e0 + PCHUNK);
  hist[t] = 0;
  __syncthreads();
  for (int e = e0 + t; e < eend; e += 256)
    atomicAdd(&hist[dst[e] >> 8], 1);
  __syncthreads();
  if (hist[t] > 0) base[t] = atomicAdd(&gcur[t], hist[t]);
  hist[t] = 0;
  __syncthreads();
  for (int e = e0 + t; e < eend; e += 256){
    int d = dst[e];
    int b = d >> 8;
    int off = atomicAdd(&hist[b], 1);
    tmp[base[b] + off] = make_int2((src[e] & 0xffff) | ((d & 255) << 16), __float_as_int(ew[e]));
  }
}

__global__ __launch_bounds__(256) void k_bsort(const int2* __restrict__ tmp, const int* __restrict__ bbase,
                                               int2* __restrict__ epair, int* __restrict__ rowptr, int N){
  __shared__ int2 ebuf[CAP];
  __shared__ int lcnt[256];
  __shared__ int sc[256];
  __shared__ int lcur[256];
  int b = blockIdx.x, t = threadIdx.x;
  int s0 = bbase[b], s1 = bbase[b + 1];
  int cnt = s1 - s0;
  lcnt[t] = 0;
  __syncthreads();
  for (int j = t; j < cnt; j += 256){
    int2 e = tmp[s0 + j];
    if (j < CAP) ebuf[j] = e;
    atomicAdd(&lcnt[(e.x >> 16) & 255], 1);
  }
  __syncthreads();
  int v = lcnt[t];
  sc[t] = v; __syncthreads();
  for (int o = 1; o < 256; o <<= 1){
    int u = (t >= o) ? sc[t - o] : 0;
    __syncthreads();
    sc[t] += u;
    __syncthreads();
  }
  int ex = sc[t] - v;
  int node = (b << 8) + t;
  if (node < N) rowptr[node] = s0 + ex;
  lcur[t] = ex;
  __syncthreads();
  for (int j = t; j < cnt; j += 256){
    int2 e = (j < CAP) ? ebuf[j] : tmp[s0 + j];
    int i = (e.x >> 16) & 255;
    int p = atomicAdd(&lcur[i], 1);
    epair[s0 + p] = make_int2(e.x & 0xffff, e.y);
  }
}

// ---------------- canonicalize per-node edge order (kills CSR placement nondeterminism) ----------------
__global__ __launch_bounds__(256) void k_sortrows(const int* __restrict__ rowptr,
                                                  int2* __restrict__ epair, int n){
  const int wave = (int)((blockIdx.x * (size_t)blockDim.x + threadIdx.x) >> 6);
  const int lane = threadIdx.x & 63;
  const int l32 = lane & 31;
  const int node = wave * 2 + (lane >> 5);
  const bool valid = node < n;
  const int nd = valid ? node : (n - 1);
  const int beg = rowptr[nd];
  const int deg = rowptr[nd + 1] - beg;
  const int dmax = max(deg, __shfl_xor(deg, 32));

  if (dmax <= 32){
    unsigned long long key = ~0ull;
    if (valid && l32 < deg){
      int2 ep = epair[beg + l32];
      key = ((unsigned long long)(unsigned)ep.y << 16) | (unsigned)(ep.x & 0xffff);
    }
    #pragma unroll
    for (int k = 2; k <= 32; k <<= 1){
      #pragma unroll
      for (int j = k >> 1; j > 0; j >>= 1){
        unsigned long long pk = __shfl_xor(key, j);   // j<32: stays within the 32-lane half
        bool up    = ((l32 & k) == 0);
        bool lower = ((l32 & j) == 0);
        unsigned long long mn = key < pk ? key : pk;
        unsigned long long mx = key < pk ? pk : key;
        key = (lower == up) ? mn : mx;
      }
    }
    if (valid && l32 < deg)
      epair[beg + l32] = make_int2((int)(key & 0xffff), (int)(unsigned)(key >> 16));
  } else {
    for (int h = 0; h < 2; h++){
      int begh = __shfl(beg, h << 5);
      int degh = __shfl(deg, h << 5);
      int vh   = __shfl((int)valid, h << 5);
      if (!vh || degh <= 0) continue;                 // wave-uniform
      int dcap = min(degh, 64);
      unsigned long long key = ~0ull;
      if (lane < dcap){
        int2 ep = epair[begh + lane];
        key = ((unsigned long long)(unsigned)ep.y << 16) | (unsigned)(ep.x & 0xffff);
      }
      #pragma unroll
      for (int k = 2; k <= 64; k <<= 1){
        #pragma unroll
        for (int j = k >> 1; j > 0; j >>= 1){
          unsigned long long pk = __shfl_xor(key, j);
          bool up    = ((lane & k) == 0);
          bool lower = ((lane & j) == 0);
          unsigned long long mn = key < pk ? key : pk;
          unsigned long long mx = key < pk ? pk : key;
          key = (lower == up) ? mn : mx;
        }
      }
      if (lane < dcap)
        epair[begh + lane] = make_int2((int)(key & 0xffff), (int)(unsigned)(key >> 16));
    }
  }
}

// ---------------- GAT GEMM via 2-term bf16 MFMA; optional fused BN on input ----------------
// Output layout: Y[n][64] (256B aligned rows, cols 0..63) + Yt[n] = {y64, y65, a_src, a_dst}.
template<bool BN_IN>
__global__ __launch_bounds__(256) void k_mm(const float* __restrict__ X, const float4* __restrict__ Xt,
    const short* __restrict__ W0, const short* __restrict__ W1,
    const float* __restrict__ att_s, const float* __restrict__ att_d,
    const float* __restrict__ bn,
    float* __restrict__ Y, float4* __restrict__ Yt, int n){
  const int wv = threadIdx.x >> 6, L = threadIdx.x & 63;
  const int quad = L >> 4, m = L & 15;
  const int row0 = blockIdx.x * 64 + wv * 16;
  const int lrow = min(row0 + m, n - 1);
  f4v acc[5];
  #pragma unroll
  for (int t = 0; t < 5; t++) acc[t] = (f4v){0.f,0.f,0.f,0.f};

  #pragma unroll
  for (int c = 0; c < 3; c++){
    float xv[8];
    if (c < 2){
      if (BN_IN){
        const float* hr = X + (size_t)lrow * D + c * 32 + quad * 8;
        #pragma unroll
        for (int j = 0; j < 8; j += 2){
          float2 hv = *(const float2*)(hr + j);
          int col = c * 32 + quad * 8 + j;
          xv[j]     = hv.x * bn[col]     + bn[D + col];
          xv[j + 1] = hv.y * bn[col + 1] + bn[D + col + 1];
        }
      } else {
        const float* xr = X + (size_t)lrow * YR;
        float4 p0 = *(const float4*)&xr[c * 32 + quad * 8];
        float4 p1 = *(const float4*)&xr[c * 32 + quad * 8 + 4];
        xv[0] = p0.x; xv[1] = p0.y; xv[2] = p0.z; xv[3] = p0.w;
        xv[4] = p1.x; xv[5] = p1.y; xv[6] = p1.z; xv[7] = p1.w;
      }
    } else {
      #pragma unroll
      for (int j = 0; j < 8; j++) xv[j] = 0.f;
      if (quad == 0){
        if (BN_IN){
          float2 hv = *(const float2*)(X + (size_t)lrow * D + 64);
          xv[0] = hv.x * bn[64] + bn[D + 64];
          xv[1] = hv.y * bn[65] + bn[D + 65];
        } else {
          float4 t = Xt[lrow];
          xv[0] = t.x; xv[1] = t.y;
        }
      }
    }
    s8v a0, a1;
    split8d(xv, a0, a1);
    const short* b0p = W0 + (c * 5) * 512 + L * 8;
    const short* b1p = W1 + (c * 5) * 512 + L * 8;
    #pragma unroll
    for (int t = 0; t < 5; t++){
      s8v b0v = *(const s8v*)(b0p + t * 512);
      s8v b1v = *(const s8v*)(b1p + t * 512);
      MM4(acc[t], a0, a1, b0v, b1v)
    }
  }

  float ps[4] = {0.f,0.f,0.f,0.f}, pd[4] = {0.f,0.f,0.f,0.f};
  #pragma unroll
  for (int t = 0; t < 5; t++){
    int col = t * 16 + m;
    float as_v = 0.f, ad_v = 0.f;
    if (col < D){ as_v = att_s[col]; ad_v = att_d[col]; }
    #pragma unroll
    for (int r = 0; r < 4; r++){
      ps[r] += acc[t][r] * as_v;
      pd[r] += acc[t][r] * ad_v;
    }
  }
  // main cols 0..63
  #pragma unroll
  for (int r = 0; r < 4; r++){
    int rw = row0 + quad * 4 + r;
    if (rw < n){
      float* yr = Y + (size_t)rw * YR;
      #pragma unroll
      for (int t = 0; t < 4; t++) yr[t * 16 + m] = acc[t][r];
    }
  }
  // col 65 lives in lane m=1; pull into m=0 (wave-uniform shuffle)
  float c65[4];
  #pragma unroll
  for (int r = 0; r < 4; r++) c65[r] = __shfl_down(acc[4][r], 1);
  #pragma unroll
  for (int o = 1; o <= 8; o <<= 1){
    #pragma unroll
    for (int r = 0; r < 4; r++){
      ps[r] += __shfl_xor(ps[r], o);
      pd[r] += __shfl_xor(pd[r], o);
    }
  }
  if (m == 0){
    #pragma unroll
    for (int r = 0; r < 4; r++){
      int rw = row0 + quad * 4 + r;
      if (rw < n) Yt[rw] = make_float4(acc[4][r], c65[r], ps[r], pd[r]);
    }
  }
}

// ---------------- Fused 5-layer FC head: 32-row blocks, t-split wave pairs, 2-term MFMA ----------------
// Activations stored in LDS PRE-SPLIT as bf16 (a0,a1) pairs (conversion 1x at write).
#define FSH 88
__global__ __launch_bounds__(256) void k_fcmm(const float* __restrict__ X, const float4* __restrict__ Xt,
    const short* __restrict__ W0, const short* __restrict__ W1,
    const float* __restrict__ bpack, float* __restrict__ out, int n){
  __shared__ __align__(16) short xa0[2][16][FSH];
  __shared__ __align__(16) short xa1[2][16][FSH];
  const int wv = threadIdx.x >> 6, L = threadIdx.x & 63;
  const int quad = L >> 4, m = L & 15;
  const int rg = wv >> 1, th = wv & 1;
  const int row0 = blockIdx.x * 32 + rg * 16;
  const int lrow = min(row0 + m, n - 1);
  const float* xr = X + (size_t)lrow * YR;

  for (int l = 0; l < 5; l++){
    const int t0 = (l == 4) ? th : (th ? 3 : 0);
    const int nt = (l == 4) ? 1  : (th ? 2 : 3);
    f4v acc[3];
    #pragma unroll
    for (int t = 0; t < 3; t++) acc[t] = (f4v){0.f,0.f,0.f,0.f};
    #pragma unroll
    for (int c = 0; c < 3; c++){
      s8v a0, a1;
      if (l == 0){
        float xv[8];
        if (c < 2){
          float4 p0 = *(const float4*)&xr[c * 32 + quad * 8];
          float4 p1 = *(const float4*)&xr[c * 32 + quad * 8 + 4];
          xv[0] = p0.x; xv[1] = p0.y; xv[2] = p0.z; xv[3] = p0.w;
          xv[4] = p1.x; xv[5] = p1.y; xv[6] = p1.z; xv[7] = p1.w;
        } else {
          #pragma unroll
          for (int j = 0; j < 8; j++) xv[j] = 0.f;
          if (quad == 0){
            float4 t = Xt[lrow];
            xv[0] = t.x; xv[1] = t.y;
          }
        }
        split8d(xv, a0, a1);
      } else {
        if (c == 2 && quad >= 2){
          a0 = (s8v){0,0,0,0,0,0,0,0};
          a1 = (s8v){0,0,0,0,0,0,0,0};
        } else {
          a0 = *(const s8v*)&xa0[rg][m][c * 32 + quad * 8];
          a1 = *(const s8v*)&xa1[rg][m][c * 32 + quad * 8];
        }
      }
      const short* b0p = W0 + ((l * 3 + c) * 5 + t0) * 512 + L * 8;
      const short* b1p = W1 + ((l * 3 + c) * 5 + t0) * 512 + L * 8;
      for (int t = 0; t < nt; t++){
        s8v b0v = *(const s8v*)(b0p + t * 512);
        s8v b1v = *(const s8v*)(b1p + t * 512);
        MM4(acc[t], a0, a1, b0v, b1v)
      }
    }
    if (l < 4){
      __syncthreads();
      for (int t = 0; t < nt; t++){
        int col = (t0 + t) * 16 + m;
        float bv = bpack[l * 80 + col];
        #pragma unroll
        for (int r = 0; r < 4; r++){
          float v = acc[t][r] + bv;
          v = v > 0.f ? v : 0.f;
          unsigned short b0 = bf16r(v);
          float r1 = v - bf16f(b0);
          xa0[rg][quad * 4 + r][col] = (short)b0;
          xa1[rg][quad * 4 + r][col] = (short)bf16r(r1);
        }
      }
      __syncthreads();
    } else {
      int col = t0 * 16 + m;
      #pragma unroll
      for (int r = 0; r < 4; r++){
        int rw = row0 + quad * 4 + r;
        if (col < 22 && rw < n) out[(size_t)rw * 22 + col] = acc[0][r] + bpack[4 * 80 + col];
      }
    }
  }
}

// ---------------- GAT softmax + aggregate ----------------
__global__ __launch_bounds__(256) void k_agg(const float* __restrict__ y, const float4* __restrict__ yt,
                                             const int* __restrict__ rowptr, const int2* __restrict__ epair,
                                             const float* __restrict__ misc, int cidx,
                                             const float* __restrict__ bias,
                                             float* __restrict__ xout, float4* __restrict__ xt, int n){
  const int wave = (int)((blockIdx.x * (size_t)blockDim.x + threadIdx.x) >> 6);
  const int lane = threadIdx.x & 63;
  const int half = lane >> 5, l32 = lane & 31;
  const int node = wave * 2 + half;
  const bool valid = node < n;
  const int nd = valid ? node : (n - 1);
  const int beg = rowptr[nd];
  const int deg = rowptr[nd + 1] - beg;
  const float ce  = misc[2 * D + cidx];
  const float adn = yt[nd].w;          // wave-uniform per half -> broadcast load
  const int dmax = max(deg, __shfl_xor(deg, 32));

  const int g = l32 >> 2, q = l32 & 3;
  float4 acc0 = make_float4(0.f,0.f,0.f,0.f);   // cols  0+4q
  float4 acc1 = make_float4(0.f,0.f,0.f,0.f);   // cols 16+4q
  float4 acc2 = make_float4(0.f,0.f,0.f,0.f);   // cols 32+4q
  float4 acc3 = make_float4(0.f,0.f,0.f,0.f);   // cols 48+4q
  float2 tacc = make_float2(0.f,0.f);           // cols 64,65 (per-lane, phase 1)

  if (dmax <= 32){
    // ---- phase 1: per-lane coef (one edge per lane); yt gather carries tail + a_src ----
    int s = 0; float coef = 0.f;
    float al = -INFINITY;
    float4 ytv = make_float4(0.f,0.f,0.f,0.f);
    if (l32 < deg){
      int2 ep = epair[beg + l32];
      s = ep.x;
      ytv = yt[s];
      al = lrelu(ytv.z + adn + ce * __int_as_float(ep.y));
    }
    float mx = al;
    #pragma unroll
    for (int o = 16; o; o >>= 1) mx = fmaxf(mx, __shfl_xor(mx, o));
    float ex = (l32 < deg) ? __expf(al - mx) : 0.f;
    float sum = ex;
    #pragma unroll
    for (int o = 16; o; o >>= 1) sum += __shfl_xor(sum, o);
    float inv = 1.f / (sum + 1e-16f);
    coef = ex * inv;
    tacc.x = coef * ytv.x;
    tacc.y = coef * ytv.y;

    // ---- hoist ALL shuffles: 4 edge-groups worth of (src, coef) per lane ----
    int   stv[4];
    float ctv[4];
    #pragma unroll
    for (int i = 0; i < 4; i++){
      int lsrc = (lane & 32) | (8 * i + g);
      stv[i] = __shfl(s,    lsrc);
      ctv[i] = __shfl(coef, lsrc);
    }
    // ---- staged gather: loads land in temps before any FMA (same per-lane predicate) ----
    float4 v0[4], v1[4], v2[4], v3[4];
    #pragma unroll
    for (int i = 0; i < 4; i++){
      if (8 * i + g < deg){
        const float* row = y + (size_t)stv[i] * YR;
        v0[i] = *(const float4*)&row[      4 * q];
        v1[i] = *(const float4*)&row[16 + 4 * q];
        v2[i] = *(const float4*)&row[32 + 4 * q];
        v3[i] = *(const float4*)&row[48 + 4 * q];
      }
    }
    #pragma unroll
    for (int i = 0; i < 4; i++){
      if (8 * i + g < deg){
        fma4(acc0, ctv[i], v0[i]);
        fma4(acc1, ctv[i], v1[i]);
        fma4(acc2, ctv[i], v2[i]);
        fma4(acc3, ctv[i], v3[i]);
      }
    }
  } else {
    // ---- rare path: deg > 32 (Poisson(20) tail) ----
    float mx = -INFINITY;
    for (int j0 = 0; j0 < dmax; j0 += 32){
      int j = j0 + l32;
      if (j < deg){
        int2 ep = epair[beg + j];
        mx = fmaxf(mx, lrelu(yt[ep.x].z + adn + ce * __int_as_float(ep.y)));
      }
    }
    #pragma unroll
    for (int o = 16; o; o >>= 1) mx = fmaxf(mx, __shfl_xor(mx, o));
    float sum = 0.f;
    for (int j0 = 0; j0 < dmax; j0 += 32){
      int j = j0 + l32;
      if (j < deg){
        int2 ep = epair[beg + j];
        sum += __expf(lrelu(yt[ep.x].z + adn + ce * __int_as_float(ep.y)) - mx);
      }
    }
    #pragma unroll
    for (int o = 16; o; o >>= 1) sum += __shfl_xor(sum, o);
    float inv = 1.f / (sum + 1e-16f);

    for (int j0 = 0; j0 < dmax; j0 += 32){
      int cs = 0; float cc = 0.f;
      int j = j0 + l32;
      if (j < deg){
        int2 ep = epair[beg + j];
        cs = ep.x;
        float4 yv = yt[cs];
        cc = __expf(lrelu(yv.z + adn + ce * __int_as_float(ep.y)) - mx) * inv;
        tacc.x += cc * yv.x;
        tacc.y += cc * yv.y;
      }
      int   stv[4];
      float ctv[4];
      #pragma unroll
      for (int i = 0; i < 4; i++){
        int lsrc = (lane & 32) | (8 * i + g);
        stv[i] = __shfl(cs, lsrc);
        ctv[i] = __shfl(cc, lsrc);
      }
      int cmax = min(32, dmax - j0);
      float4 v0[4], v1[4], v2[4], v3[4];
      #pragma unroll
      for (int i = 0; i < 4; i++){
        int e = 8 * i + g;
        if (j0 + e < deg && e < cmax){
          const float* row = y + (size_t)stv[i] * YR;
          v0[i] = *(const float4*)&row[      4 * q];
          v1[i] = *(const float4*)&row[16 + 4 * q];
          v2[i] = *(const float4*)&row[32 + 4 * q];
          v3[i] = *(const float4*)&row[48 + 4 * q];
        }
      }
      #pragma unroll
      for (int i = 0; i < 4; i++){
        int e = 8 * i + g;
        if (j0 + e < deg && e < cmax){
          fma4(acc0, ctv[i], v0[i]);
          fma4(acc1, ctv[i], v1[i]);
          fma4(acc2, ctv[i], v2[i]);
          fma4(acc3, ctv[i], v3[i]);
        }
      }
    }
  }

  // tail reduce: contributions are per-lane (all 32), fold bits 0,1 first
  tacc.x += __shfl_xor(tacc.x, 1); tacc.y += __shfl_xor(tacc.y, 1);
  tacc.x += __shfl_xor(tacc.x, 2); tacc.y += __shfl_xor(tacc.y, 2);
  // reduce over the 8 edge-groups (lane bits 2,3,4 within the half)
  #pragma unroll
  for (int o = 4; o <= 16; o <<= 1){
    acc0.x += __shfl_xor(acc0.x, o); acc0.y += __shfl_xor(acc0.y, o);
    acc0.z += __shfl_xor(acc0.z, o); acc0.w += __shfl_xor(acc0.w, o);
    acc1.x += __shfl_xor(acc1.x, o); acc1.y += __shfl_xor(acc1.y, o);
    acc1.z += __shfl_xor(acc1.z, o); acc1.w += __shfl_xor(acc1.w, o);
    acc2.x += __shfl_xor(acc2.x, o); acc2.y += __shfl_xor(acc2.y, o);
    acc2.z += __shfl_xor(acc2.z, o); acc2.w += __shfl_xor(acc2.w, o);
    acc3.x += __shfl_xor(acc3.x, o); acc3.y += __shfl_xor(acc3.y, o);
    acc3.z += __shfl_xor(acc3.z, o); acc3.w += __shfl_xor(acc3.w, o);
    tacc.x += __shfl_xor(tacc.x, o); tacc.y += __shfl_xor(tacc.y, o);
  }
  if (valid){
    float* orow = xout + (size_t)node * YR;
    if (l32 < 4){
      int c0 = 4 * l32;
      float4 v;
      v.x = acc0.x + bias[c0+0]; v.x = v.x > 0.f ? v.x : 0.f;
      v.y = acc0.y + bias[c0+1]; v.y = v.y > 0.f ? v.y : 0.f;
      v.z = acc0.z + bias[c0+2]; v.z = v.z > 0.f ? v.z : 0.f;
      v.w = acc0.w + bias[c0+3]; v.w = v.w > 0.f ? v.w : 0.f;
      *(float4*)&orow[c0] = v;
      v.x = acc1.x + bias[16+c0+0]; v.x = v.x > 0.f ? v.x : 0.f;
      v.y = acc1.y + bias[16+c0+1]; v.y = v.y > 0.f ? v.y : 0.f;
      v.z = acc1.z + bias[16+c0+2]; v.z = v.z > 0.f ? v.z : 0.f;
      v.w = acc1.w + bias[16+c0+3]; v.w = v.w > 0.f ? v.w : 0.f;
      *(float4*)&orow[16 + c0] = v;
      v.x = acc2.x + bias[32+c0+0]; v.x = v.x > 0.f ? v.x : 0.f;
      v.y = acc2.y + bias[32+c0+1]; v.y = v.y > 0.f ? v.y : 0.f;
      v.z = acc2.z + bias[32+c0+2]; v.z = v.z > 0.f ? v.z : 0.f;
      v.w = acc2.w + bias[32+c0+3]; v.w = v.w > 0.f ? v.w : 0.f;
      *(float4*)&orow[32 + c0] = v;
      v.x = acc3.x + bias[48+c0+0]; v.x = v.x > 0.f ? v.x : 0.f;
      v.y = acc3.y + bias[48+c0+1]; v.y = v.y > 0.f ? v.y : 0.f;
      v.z = acc3.z + bias[48+c0+2]; v.z = v.z > 0.f ? v.z : 0.f;
      v.w = acc3.w + bias[48+c0+3]; v.w = v.w > 0.f ? v.w : 0.f;
      *(float4*)&orow[48 + c0] = v;
    }
    if (l32 == 0){
      float tx = tacc.x + bias[64]; tx = tx > 0.f ? tx : 0.f;
      float ty = tacc.y + bias[65]; ty = ty > 0.f ? ty : 0.f;
      xt[node] = make_float4(tx, ty, 0.f, 0.f);
    }
  }
}

// ---------------- launch ----------------
extern "C" void kernel_launch(void* const* d_in, const int* in_sizes, int n_in,
                              void* d_out, int out_size, void* d_ws, size_t ws_size,
                              hipStream_t stream){
  const float* h     = (const float*)d_in[0];
  const int*   ei    = (const int*)  d_in[1];
  const float* ew    = (const float*)d_in[2];
  const float* gamma = (const float*)d_in[3];
  const float* beta  = (const float*)d_in[4];
  const float *Wl[3], *bl[3], *asl[3], *adl[3], *Wel[3], *ael[3];
  int idx = 5;
  for (int l = 0; l < 3; l++){
    Wl[l]  = (const float*)d_in[idx++];
    bl[l]  = (const float*)d_in[idx++];
    asl[l] = (const float*)d_in[idx++];
    adl[l] = (const float*)d_in[idx++];
    Wel[l] = (const float*)d_in[idx++];
    ael[l] = (const float*)d_in[idx++];
  }
  const float *fw[5], *fb[5];
  for (int l = 0; l < 5; l++){ fw[l] = (const float*)d_in[idx++]; fb[l] = (const float*)d_in[idx++]; }

  int N = in_sizes[0] / D;
  int E = in_sizes[1] / 2;
  const int* src  = ei;
  const int* dstp = ei + E;

  char* base = (char*)d_ws;
  size_t o = 0;
  auto alloc = [&](size_t b){ size_t r = o; o += (b + 255) & ~(size_t)255; return r; };
  float*  bufA   = (float*)(base + alloc((size_t)N * YR * 4));
  float*  bufB   = (float*)(base + alloc((size_t)N * YR * 4));
  float4* tA     = (float4*)(base + alloc((size_t)N * 16));
  float4* tB     = (float4*)(base + alloc((size_t)N * 16));
  float*  misc   = (float*)(base + alloc(512 * 4));
  float*  partials = (float*)(base + alloc(2 * D * 256 * 4));   // [col][256] col-major
  int*    rowptr = (int*)  (base + alloc((size_t)(N + 1) * 4));
  int*    bhist  = (int*)  (base + alloc(256 * 4));
  int*    bbase  = (int*)  (base + alloc(257 * 4));
  int*    gcur   = (int*)  (base + alloc(256 * 4));
  int2*   epair  = (int2*) (base + alloc((size_t)E * 8));
  short*  W0p    = (short*)(base + alloc(3 * 7680 * 2));
  short*  W1p    = (short*)(base + alloc(3 * 7680 * 2));
  short*  FW0p   = (short*)(base + alloc(5 * 7680 * 2));
  short*  FW1p   = (short*)(base + alloc(5 * 7680 * 2));
  float*  bpack  = (float*)(base + alloc(400 * 4));
  int2*   tmp    = (int2*)bufB;   // alias: bufB (12.8 MB) unused until first k_mm; E*8 = 8 MB fits

  hipMemsetAsync(bhist, 0, 256 * 4, stream);   // partials need no init (fully written)

  k_stats_hist<<<512, 256, 0, stream>>>(h, dstp, partials, bhist, N, E);

  PrepArgs pa;
  pa.part = partials; pa.gamma = gamma; pa.beta = beta;
  for (int l = 0; l < 3; l++){ pa.We[l] = Wel[l]; pa.ae[l] = ael[l]; pa.gw[l] = Wl[l]; }
  for (int l = 0; l < 5; l++){ pa.fw[l] = fw[l]; pa.fb[l] = fb[l]; }
  pa.misc = misc; pa.W0 = W0p; pa.W1 = W1p;
  pa.F0 = FW0p; pa.F1 = FW1p; pa.bpack = bpack; pa.n = N;
  k_prep<<<34, 256, 0, stream>>>(pa);

  int NB = (N + 255) >> 8;
  k_bscan<<<1, 256, 0, stream>>>(bhist, bbase, gcur, rowptr, N, E);
  k_part<<<(E + PCHUNK - 1) / PCHUNK, 256, 0, stream>>>(src, dstp, ew, gcur, tmp, E);
  k_bsort<<<NB, 256, 0, stream>>>(tmp, bbase, epair, rowptr, N);

  int gb = (N + 63) / 64;
  int ab = (N + 7) / 8;   // 2 nodes per wave, 4 waves per block

  k_sortrows<<<ab, 256, 0, stream>>>(rowptr, epair, N);   // canonical edge order

  k_mm<true ><<<gb, 256, 0, stream>>>(h,    nullptr, W0p + 0 * 7680, W1p + 0 * 7680,
                                      asl[0], adl[0], misc, bufB, tB, N);
  k_agg<<<ab, 256, 0, stream>>>(bufB, tB, rowptr, epair, misc, 0, bl[0], bufA, tA, N);
  k_mm<false><<<gb, 256, 0, stream>>>(bufA, tA, W0p + 1 * 7680, W1p + 1 * 7680,
                                      asl[1], adl[1], misc, bufB, tB, N);
  k_agg<<<ab, 256, 0, stream>>>(bufB, tB, rowptr, epair, misc, 1, bl[1], bufA, tA, N);
  k_mm<false><<<gb, 256, 0, stream>>>(bufA, tA, W0p + 2 * 7680, W1p + 2 * 7680,
                                      asl[2], adl[2], misc, bufB, tB, N);
  k_agg<<<ab, 256, 0, stream>>>(bufB, tB, rowptr, epair, misc, 2, bl[2], bufA, tA, N);

  int gb2 = (N + 31) / 32;
  k_fcmm<<<gb2, 256, 0, stream>>>(bufA, tA, FW0p, FW1p, bpack, (float*)d_out, N);
}